// Round 18
// baseline (116.507 us; speedup 1.0000x reference)
//
#include <hip/hip_runtime.h>
#include <hip/hip_bf16.h>
#include <math.h>

#define NB 2
#define SS 2048
#define HH 1024
#define NHEAD 16
#define HDIM 64
#define NTOK (NB * SS)  // 4096

#define QSCALE 0.18033688011112042f   // 0.125 * log2(e)

typedef __attribute__((ext_vector_type(8))) short short8;
typedef __attribute__((ext_vector_type(4))) float f32x4;
typedef __attribute__((ext_vector_type(16))) float f32x16;

// byte-offset swizzles: XOR 16B-chunk index with low row bits
#define SWZ16(row, boff) ((boff) ^ (((row) & 7) << 4))    // 128B rows (8 chunks)
#define VSWZ(row, boff)  ((boff) ^ (((row) & 15) << 4))   // 256B rows (16 chunks)

// f32 -> bf16 round-to-nearest-even
__device__ __forceinline__ unsigned short f2b(float x) {
    union { float f; unsigned int u; } v; v.f = x;
    unsigned int u = v.u + 0x7fff + ((v.u >> 16) & 1);
    return (unsigned short)(u >> 16);
}

// pack two f32 -> one dword of 2 bf16 via HW instruction (T12)
__device__ __forceinline__ unsigned pk2a(float lo, float hi) {
    unsigned r;
    asm("v_cvt_pk_bf16_f32 %0, %1, %2" : "=v"(r) : "v"(lo), "v"(hi));
    return r;
}

__device__ __forceinline__ float exp2fast(float x) {
#if __has_builtin(__builtin_amdgcn_exp2f)
    return __builtin_amdgcn_exp2f(x);
#else
    return exp2f(x);
#endif
}

// async global->LDS, 16B per lane
__device__ __forceinline__ void gl16(const void* g, void* l) {
    __builtin_amdgcn_global_load_lds(
        (const __attribute__((address_space(1))) void*)g,
        (__attribute__((address_space(3))) void*)l, 16, 0, 0);
}

// ---------------------------------------------------------------------------
// Fused prep: blocks [0,2048) cvt_hs; [2048,3072) transpose_w; [3072,3074)
// mask_scan.
// ---------------------------------------------------------------------------
__global__ __launch_bounds__(256) void prep(
    const float* __restrict__ hs,
    const float* __restrict__ mask,
    const float* __restrict__ W0, const float* __restrict__ W1,
    const float* __restrict__ W2, const float* __restrict__ W3,
    unsigned short* __restrict__ Ab,
    unsigned short* __restrict__ Wt,
    int* __restrict__ idx, float* __restrict__ bias, int* __restrict__ cnt)
{
    __shared__ unsigned short T[64][72];
    __shared__ int part[256];
    const int bid = blockIdx.x;
    const int tid = threadIdx.x;

    if (bid < 2048) {
        const size_t i = ((size_t)bid * 256 + tid) * 8;
        float4 v0 = *(const float4*)(hs + i);
        float4 v1 = *(const float4*)(hs + i + 4);
        short8 o;
        o[0] = f2b(v0.x); o[1] = f2b(v0.y); o[2] = f2b(v0.z); o[3] = f2b(v0.w);
        o[4] = f2b(v1.x); o[5] = f2b(v1.y); o[6] = f2b(v1.z); o[7] = f2b(v1.w);
        *(short8*)(Ab + i) = o;
    } else if (bid < 3072) {
        const int t = bid - 2048;
        const int z = t >> 8;
        const int n0 = (t & 15) * 64, k0 = ((t >> 4) & 15) * 64;
        const float* W = z == 0 ? W0 : z == 1 ? W1 : z == 2 ? W2 : W3;
        unsigned short* dst = Wt + (size_t)z * HH * HH;
        {
            const int r = tid >> 2, c4 = (tid & 3) * 16;
            const float* src = W + (size_t)(k0 + r) * HH + n0 + c4;
#pragma unroll
            for (int j = 0; j < 16; j += 4) {
                float4 v = *(const float4*)(src + j);
                T[c4 + j + 0][r] = f2b(v.x); T[c4 + j + 1][r] = f2b(v.y);
                T[c4 + j + 2][r] = f2b(v.z); T[c4 + j + 3][r] = f2b(v.w);
            }
        }
        __syncthreads();
        {
            const int n = tid >> 2, sc = (tid & 3) * 2;
#pragma unroll
            for (int u = 0; u < 2; ++u) {
                short8 v = *(const short8*)&T[n][(sc + u) * 8];
                *(short8*)(dst + (size_t)(n0 + n) * HH + k0 + (sc + u) * 8) = v;
            }
        }
    } else {
        const int b = bid - 3072;
        int loc[8]; int m = 0;
        const float* mp = mask + (size_t)b * SS + tid * 8;
#pragma unroll
        for (int j = 0; j < 8; ++j) { loc[j] = (mp[j] == 0.0f) ? 1 : 0; m += loc[j]; }
        part[tid] = m;
        __syncthreads();
        for (int d = 1; d < 256; d <<= 1) {
            int v = (tid >= d) ? part[tid - d] : 0;
            __syncthreads();
            part[tid] += v;
            __syncthreads();
        }
        int base = part[tid] - m;
        const int total = part[255];
#pragma unroll
        for (int j = 0; j < 8; ++j)
            if (loc[j]) idx[(size_t)b * SS + (base++)] = tid * 8 + j;
        if (tid == 0) cnt[b] = total;
        __syncthreads();
        for (int j = tid; j < SS; j += 256) {
            if (j >= total) idx[(size_t)b * SS + j] = 0;
            bias[(size_t)b * SS + j] = (j < total) ? 0.0f : -1e30f;
        }
    }
}

// ---------------------------------------------------------------------------
// QKV GEMM: block = 2 waves (128 thr), tile 128(M)x128(N), per-wave 64x128
// (4 A-frags + 8 B-frags = 12 ds_reads per 32 MFMA -> 2.67 MFMA/read).
// BK=32 double-buffered, counted vmcnt(8), raw s_barrier. Grid 768 = 3/CU.
// ---------------------------------------------------------------------------
__global__ __launch_bounds__(128) void gemm_qkv(
    const unsigned short* __restrict__ A, const unsigned short* __restrict__ Bt,
    const float* __restrict__ b0, const float* __restrict__ b1,
    const float* __restrict__ b2, unsigned short* __restrict__ Cout)
{
    __shared__ __align__(16) unsigned short As[2][128 * 32];
    __shared__ __align__(16) unsigned short Bs[2][128 * 32];

    const int tid = threadIdx.x;
    const int w  = tid >> 6;        // wave 0..1 (M-split)
    const int l  = tid & 63;
    const int g  = l >> 4, c = l & 15;
    const int m0 = blockIdx.y * 128, n0 = blockIdx.x * 128;

    // staging map: per gl16 call a wave covers 16 rows x 4 chunks (64B rows)
    const int r4  = l >> 2;                 // row within 16-row group * 4
    const int gch = (l & 3) ^ (r4 & 3);     // inverse-swizzled global chunk

    f32x4 acc[4][8];
#pragma unroll
    for (int mi = 0; mi < 4; ++mi)
#pragma unroll
        for (int ni = 0; ni < 8; ++ni)
            acc[mi][ni] = (f32x4){0.f, 0.f, 0.f, 0.f};

    // per stage: each wave stages its half of As (64 rows) + half of Bs
#define STAGE(kt_, bb) {                                                      \
    _Pragma("unroll")                                                         \
    for (int u_ = 0; u_ < 4; ++u_) {                                          \
        const int rb_ = w * 64 + u_ * 16;                                     \
        gl16(A  + (size_t)(m0 + rb_ + r4) * HH + (kt_) * 32 + gch * 8,        \
             (void*)&As[bb][rb_ * 32]);                                       \
        gl16(Bt + (size_t)(n0 + rb_ + r4) * HH + (kt_) * 32 + gch * 8,        \
             (void*)&Bs[bb][rb_ * 32]);                                       \
    } }

    STAGE(0, 0);          //  8 loads/thread in flight
    STAGE(1, 1);          // 16 in flight

    for (int kt = 0; kt < 32; ++kt) {
        const int cb = kt & 1;
        if (kt < 31) asm volatile("s_waitcnt vmcnt(8)" ::: "memory");
        else         asm volatile("s_waitcnt vmcnt(0)" ::: "memory");
        __builtin_amdgcn_s_barrier();
        __builtin_amdgcn_sched_barrier(0);

        short8 af[4], bf[8];
#pragma unroll
        for (int mi = 0; mi < 4; ++mi) {
            const int row = w * 64 + mi * 16 + c;
            af[mi] = *(const short8*)&As[cb][row * 32 + ((g * 8) ^ ((c & 3) * 8))];
        }
#pragma unroll
        for (int ni = 0; ni < 8; ++ni) {
            const int row = ni * 16 + c;
            bf[ni] = *(const short8*)&Bs[cb][row * 32 + ((g * 8) ^ ((c & 3) * 8))];
        }
        __builtin_amdgcn_s_setprio(1);
#pragma unroll
        for (int mi = 0; mi < 4; ++mi)
#pragma unroll
            for (int ni = 0; ni < 8; ++ni)
                acc[mi][ni] = __builtin_amdgcn_mfma_f32_16x16x32_bf16(
                    af[mi], bf[ni], acc[mi][ni], 0, 0, 0);
        __builtin_amdgcn_s_setprio(0);

        __builtin_amdgcn_sched_barrier(0);
        __builtin_amdgcn_s_barrier();
        __builtin_amdgcn_sched_barrier(0);
        if (kt + 2 < 32) STAGE(kt + 2, cb);
    }
#undef STAGE

    const int which = n0 >> 10;   // block-uniform (128 | 1024)
    const float* bp = which == 0 ? b0 : which == 1 ? b1 : b2;
    const float scl = which == 0 ? QSCALE : 1.0f;
    unsigned short* dst = Cout + (size_t)which * NTOK * HH;
#pragma unroll
    for (int ni = 0; ni < 8; ++ni) {
        const int nl = (n0 + ni * 16 + c) & 1023;
        const int h = nl >> 6, d = nl & 63;
        const float bv = bp[nl];
#pragma unroll
        for (int mi = 0; mi < 4; ++mi) {
            const int mBase = m0 + w * 64 + mi * 16 + g * 4;
#pragma unroll
            for (int j = 0; j < 4; ++j) {
                const int m = mBase + j;
                const int b = m >> 11, si = m & 2047;
                dst[(((size_t)(b * 16 + h)) * SS + si) * 64 + d] =
                    f2b((acc[mi][ni][j] + bv) * scl);
            }
        }
    }
}

// ---------------------------------------------------------------------------
// Out-proj GEMM: 128(M)x64(N) tiles, BK=64 dbuf, counted vmcnt(6).
// Grid (16,32) = 512 blocks -> 2 blocks/CU.
// ---------------------------------------------------------------------------
__global__ __launch_bounds__(256) void gemm_out(
    const unsigned short* __restrict__ A, const unsigned short* __restrict__ Bt,
    const float* __restrict__ b0, float* __restrict__ Cout)
{
    __shared__ __align__(16) unsigned short As[2][128 * 64];
    __shared__ __align__(16) unsigned short Bs[2][64 * 64];

    const int tid = threadIdx.x;
    const int w  = tid >> 6;
    const int l  = tid & 63;
    const int g  = l >> 4, c = l & 15;
    const int wr = w >> 1, wc = w & 1;
    const int m0 = blockIdx.y * 128, n0 = blockIdx.x * 64;

    const int dr = l >> 3;
    const int gc = (l & 7) ^ dr;

    const unsigned short* aBase = A  + (size_t)(m0 + w * 32 + dr) * HH + gc * 8;

    f32x4 acc[4][2];
#pragma unroll
    for (int mi = 0; mi < 4; ++mi)
#pragma unroll
        for (int ni = 0; ni < 2; ++ni)
            acc[mi][ni] = (f32x4){0.f, 0.f, 0.f, 0.f};

    const int swz = (c & 7) * 8;

#define STAGE(kt_, bb) {                                                      \
    const int koff = (kt_) * 64;                                              \
    _Pragma("unroll")                                                         \
    for (int i_ = 0; i_ < 4; ++i_)                                            \
        gl16(aBase + koff + (size_t)i_ * 8 * HH, (void*)&As[bb][(w*4+i_)*512]); \
    _Pragma("unroll")                                                         \
    for (int u_ = 0; u_ < 2; ++u_) {                                          \
        const int rb_ = (w * 2 + u_) * 8;                                     \
        gl16(Bt + (size_t)(n0 + rb_ + dr) * HH + koff + gc * 8,               \
             (void*)&Bs[bb][rb_ * 64]);                                       \
    } }

    STAGE(0, 0);
    STAGE(1, 1);

    for (int kt = 0; kt < 16; ++kt) {
        const int cb = kt & 1;
        if (kt < 15) asm volatile("s_waitcnt vmcnt(6)" ::: "memory");
        else         asm volatile("s_waitcnt vmcnt(0)" ::: "memory");
        __builtin_amdgcn_s_barrier();
        __builtin_amdgcn_sched_barrier(0);

        short8 af[2][4], bf[2][2];
#pragma unroll
        for (int ks = 0; ks < 2; ++ks) {
            const int kb = ks * 32;
#pragma unroll
            for (int mi = 0; mi < 4; ++mi) {
                const int row = wr * 64 + mi * 16 + c;
                af[ks][mi] = *(const short8*)&As[cb][row * 64 + ((kb + g * 8) ^ swz)];
            }
#pragma unroll
            for (int ni = 0; ni < 2; ++ni) {
                const int row = wc * 32 + ni * 16 + c;
                bf[ks][ni] = *(const short8*)&Bs[cb][row * 64 + ((kb + g * 8) ^ swz)];
            }
        }
        __builtin_amdgcn_s_setprio(1);
#pragma unroll
        for (int ks = 0; ks < 2; ++ks)
#pragma unroll
            for (int mi = 0; mi < 4; ++mi)
#pragma unroll
                for (int ni = 0; ni < 2; ++ni)
                    acc[mi][ni] = __builtin_amdgcn_mfma_f32_16x16x32_bf16(
                        af[ks][mi], bf[ks][ni], acc[mi][ni], 0, 0, 0);
        __builtin_amdgcn_s_setprio(0);

        __builtin_amdgcn_sched_barrier(0);
        __builtin_amdgcn_s_barrier();
        __builtin_amdgcn_sched_barrier(0);
        if (kt + 2 < 16) STAGE(kt + 2, cb);
    }
#undef STAGE

#pragma unroll
    for (int ni = 0; ni < 2; ++ni) {
        const int n = n0 + wc * 32 + ni * 16 + c;
        const float bv = b0[n];
#pragma unroll
        for (int mi = 0; mi < 4; ++mi) {
            const int mBase = m0 + wr * 64 + mi * 16 + g * 4;
#pragma unroll
            for (int j = 0; j < 4; ++j)
                Cout[(size_t)(mBase + j) * HH + n] = acc[mi][ni][j] + bv;
        }
    }
}

// ---------------------------------------------------------------------------
// V head-major [bh][s][64] -> Vt [bh][64][j] GATHERED along unmasked idx
// ---------------------------------------------------------------------------
__global__ __launch_bounds__(256) void vtrans(
    const unsigned short* __restrict__ Vh, const int* __restrict__ idx,
    unsigned short* __restrict__ Vt)
{
    __shared__ unsigned short T[64][72];
    const int tid = threadIdx.x;
    const int bh = blockIdx.y;
    const int b  = bh >> 4;
    const int s0 = blockIdx.x * 64;
    {
        const int r = tid >> 2, dc = (tid & 3) * 16;
        const int sidx = idx[(size_t)b * SS + s0 + r];
        const unsigned short* src = Vh + ((size_t)bh * SS + sidx) * 64 + dc;
        short8 v0 = *(const short8*)src;
        short8 v1 = *(const short8*)(src + 8);
#pragma unroll
        for (int j = 0; j < 8; ++j) {
            T[dc + j][r]     = (unsigned short)v0[j];
            T[dc + 8 + j][r] = (unsigned short)v1[j];
        }
    }
    __syncthreads();
    {
        const int d = tid >> 2, sc = (tid & 3) * 2;
#pragma unroll
        for (int u = 0; u < 2; ++u) {
            short8 v = *(const short8*)&T[d][(sc + u) * 8];
            *(short8*)(Vt + ((size_t)bh * 64 + d) * SS + s0 + (sc + u) * 8) = v;
        }
    }
}

// ---------------------------------------------------------------------------
// Flash attention over COMPACTED keys (exact). Swapped-QK^T 32x32x16,
// no-max log2 softmax, 4 waves x 32q = 128 q/block. 128-KEY double-buffered
// tiles, reg-staged prefetch (T14), K gathered via idx at stage time.
// Bias only on boundary tile. LDS 64KB -> 2 blocks/CU. Grid 512, XCD T1.
// ---------------------------------------------------------------------------
__global__ __launch_bounds__(256) void attn_mfma(
    const unsigned short* __restrict__ Qb, const unsigned short* __restrict__ Kb,
    const unsigned short* __restrict__ Vtb, const float* __restrict__ biasg,
    const int* __restrict__ idxg, const int* __restrict__ cntg,
    unsigned short* __restrict__ ctx)
{
    __shared__ __align__(16) unsigned short Ks[2][128 * 64];   // [key][d] 128B rows
    __shared__ __align__(16) unsigned short Vts[2][64 * 128];  // [d][key] 256B rows
    __shared__ float Sc[4][32];

    const int wg  = blockIdx.x;
    const int swg = (wg & 7) * 64 + (wg >> 3);
    const int qx  = swg & 15;
    const int bh  = swg >> 4;

    const int tid = threadIdx.x;
    const int l   = tid & 63;
    const int wq  = tid >> 6;
    const int hi  = l >> 5;
    const int c   = l & 31;
    const int b   = bh >> 4, h = bh & 15;
    const int q0  = qx * 128 + wq * 32;

    const unsigned short* Qp = Qb  + (size_t)bh * SS * 64;
    const unsigned short* Kp = Kb  + (size_t)bh * SS * 64;
    const unsigned short* Vp = Vtb + (size_t)bh * 64 * SS;
    const float* biasp = biasg + (size_t)b * SS;
    const int* idxb = idxg + (size_t)b * SS;

    const int cnt    = cntg[b];
    const int nt     = (cnt + 127) >> 7;   // 128-key tiles (<= 16)
    const int ntFull = cnt >> 7;           // fully-real tiles

    // staging maps
    const int sr  = tid >> 3;        // K rows: sr + 32u, u=0..3
    const int sc8 = tid & 7;         // K 16B chunk (of 8)
    const int vd  = tid >> 2;        // V^T row (d) 0..63
    const int vc0 = (tid & 3) * 4;   // V 16B chunks vc0+u (of 16)

    short8 qf[4];
    {
        const unsigned short* qrow = Qp + (size_t)(q0 + c) * 64 + hi * 8;
#pragma unroll
        for (int s = 0; s < 4; ++s) qf[s] = *(const short8*)(qrow + s * 16);
    }

    f32x16 oacc[2];
#pragma unroll
    for (int dt = 0; dt < 2; ++dt)
#pragma unroll
        for (int r = 0; r < 16; ++r) oacc[dt][r] = 0.f;

    float ls[4] = {0.f, 0.f, 0.f, 0.f};

    short8 kr0, kr1, kr2, kr3, vr0, vr1, vr2, vr3;

#define LOADREG(t_) {                                                         \
    const int* ip_ = idxb + (t_) * 128;                                       \
    kr0 = *(const short8*)(Kp + (size_t)ip_[sr      ] * 64 + sc8 * 8);        \
    kr1 = *(const short8*)(Kp + (size_t)ip_[sr + 32 ] * 64 + sc8 * 8);        \
    kr2 = *(const short8*)(Kp + (size_t)ip_[sr + 64 ] * 64 + sc8 * 8);        \
    kr3 = *(const short8*)(Kp + (size_t)ip_[sr + 96 ] * 64 + sc8 * 8);        \
    const unsigned short* vp_ = Vp + (size_t)vd * SS + (t_) * 128;            \
    vr0 = *(const short8*)(vp_ + (vc0 + 0) * 8);                              \
    vr1 = *(const short8*)(vp_ + (vc0 + 1) * 8);                              \
    vr2 = *(const short8*)(vp_ + (vc0 + 2) * 8);                              \
    vr3 = *(const short8*)(vp_ + (vc0 + 3) * 8); }

#define DSWRITE(bb) {                                                         \
    *(short8*)((char*)Ks[bb] + (sr      ) * 128 + SWZ16(sr,      sc8 * 16)) = kr0; \
    *(short8*)((char*)Ks[bb] + (sr + 32 ) * 128 + SWZ16(sr + 32, sc8 * 16)) = kr1; \
    *(short8*)((char*)Ks[bb] + (sr + 64 ) * 128 + SWZ16(sr + 64, sc8 * 16)) = kr2; \
    *(short8*)((char*)Ks[bb] + (sr + 96 ) * 128 + SWZ16(sr + 96, sc8 * 16)) = kr3; \
    *(short8*)((char*)Vts[bb] + vd * 256 + VSWZ(vd, (vc0 + 0) * 16)) = vr0;   \
    *(short8*)((char*)Vts[bb] + vd * 256 + VSWZ(vd, (vc0 + 1) * 16)) = vr1;   \
    *(short8*)((char*)Vts[bb] + vd * 256 + VSWZ(vd, (vc0 + 2) * 16)) = vr2;   \
    *(short8*)((char*)Vts[bb] + vd * 256 + VSWZ(vd, (vc0 + 3) * 16)) = vr3; }

    LOADREG(0);
    DSWRITE(0);
    __syncthreads();

    for (int t = 0; t < nt; ++t) {
        const int cb = t & 1;
        if (t + 1 < nt) LOADREG(t + 1);   // in flight during compute
        const bool needBias = (t >= ntFull);

#pragma unroll
        for (int hh = 0; hh < 4; ++hh) {   // four 32-key halves
            f32x16 s4h;
#pragma unroll
            for (int r = 0; r < 16; ++r) s4h[r] = 0.f;
            const int krow = hh * 32 + c;
            __builtin_amdgcn_s_setprio(1);
#pragma unroll
            for (int ss = 0; ss < 4; ++ss) {
                short8 kf = *(const short8*)((char*)Ks[cb] + krow * 128 +
                                             SWZ16(krow, (ss * 2 + hi) * 16));
                s4h = __builtin_amdgcn_mfma_f32_32x32x16_bf16(kf, qf[ss], s4h, 0, 0, 0);
            }
            __builtin_amdgcn_s_setprio(0);

            float pvv[16];
            if (needBias) {
                f32x4 mqh[4];
#pragma unroll
                for (int tt = 0; tt < 4; ++tt)
                    mqh[tt] = *(const f32x4*)(biasp + t * 128 + hh * 32 + tt * 8 + hi * 4);
#pragma unroll
                for (int r = 0; r < 16; ++r)
                    pvv[r] = exp2fast(s4h[r] + mqh[r >> 2][r & 3]);
            } else {
#pragma unroll
                for (int r = 0; r < 16; ++r)
                    pvv[r] = exp2fast(s4h[r]);
            }
#pragma unroll
            for (int r = 0; r < 16; ++r) ls[r & 3] += pvv[r];

            unsigned wdh[8];
#pragma unroll
            for (int j = 0; j < 8; ++j) wdh[j] = pk2a(pvv[2 * j], pvv[2 * j + 1]);
#pragma unroll
            for (int g4 = 0; g4 < 2; ++g4) {
                asm volatile("v_permlane32_swap_b32 %0, %1"
                             : "+v"(wdh[4 * g4 + 0]), "+v"(wdh[4 * g4 + 2]));
                asm volatile("v_permlane32_swap_b32 %0, %1"
                             : "+v"(wdh[4 * g4 + 1]), "+v"(wdh[4 * g4 + 3]));
            }

            __builtin_amdgcn_s_setprio(1);
#pragma unroll
            for (int s2 = 0; s2 < 2; ++s2) {
                const int vchunk = hh * 4 + s2 * 2 + hi;   // 16-key slice (of 16)
                union { unsigned u[4]; short8 s8; } pa;
#pragma unroll
                for (int u_ = 0; u_ < 4; ++u_) pa.u[u_] = wdh[4 * s2 + u_];
#pragma unroll
                for (int dt = 0; dt < 2; ++dt) {
                    const int vrow = dt * 32 + c;
                    short8 vf = *(const short8*)((char*)Vts[cb] + vrow * 256 +
                                                 VSWZ(vrow, vchunk * 16));
                    oacc[dt] = __builtin_amdgcn_mfma_f32_32x32x16_bf16(pa.s8, vf, oacc[dt], 0, 0, 0);
                }
            }
            __builtin_amdgcn_s_setprio(0);
        }

        if (t + 1 < nt) DSWRITE(cb ^ 1);   // buffer not being read this iter
        __syncthreads();                   // writes visible; all reads of cb done
    }
#undef LOADREG
#undef DSWRITE

    // ---- epilogue: per-wave l reduce + broadcast to D-row layout ----
    float lsum = (ls[0] + ls[1]) + (ls[2] + ls[3]);
    lsum += __shfl_xor(lsum, 32, 64);

    Sc[wq][c] = lsum;
    asm volatile("s_waitcnt lgkmcnt(0)" ::: "memory");
    f32x4 lq[4];
#pragma unroll
    for (int tt = 0; tt < 4; ++tt)
        lq[tt] = *(const f32x4*)&Sc[wq][tt * 8 + hi * 4];

#pragma unroll
    for (int dt = 0; dt < 2; ++dt)
#pragma unroll
        for (int r = 0; r < 16; ++r) {
            const int row = (r & 3) + 8 * (r >> 2) + 4 * hi;
            const float val = oacc[dt][r] / lq[r >> 2][r & 3];
            ctx[((size_t)(b * SS + q0 + row)) * HH + h * 64 + dt * 32 + c] = f2b(val);
        }
}

// ---------------------------------------------------------------------------
extern "C" void kernel_launch(void* const* d_in, const int* in_sizes, int n_in,
                              void* d_out, int out_size, void* d_ws, size_t ws_size,
                              hipStream_t stream)
{
    const float* hs   = (const float*)d_in[0];
    const float* mask = (const float*)d_in[1];
    const float* Wq   = (const float*)d_in[2];
    const float* bq   = (const float*)d_in[3];
    const float* Wk   = (const float*)d_in[4];
    const float* bk   = (const float*)d_in[5];
    const float* Wv   = (const float*)d_in[6];
    const float* bv   = (const float*)d_in[7];
    const float* Wo   = (const float*)d_in[8];
    const float* bo   = (const float*)d_in[9];
    float* out = (float*)d_out;

    unsigned short* Ab   = (unsigned short*)d_ws;
    unsigned short* Wt   = Ab + (size_t)NTOK * HH;
    unsigned short* Qh   = Wt + (size_t)4 * HH * HH;   // Qh|Kh|Vh contiguous
    unsigned short* Kh   = Qh + (size_t)NTOK * HH;
    unsigned short* Vh   = Kh + (size_t)NTOK * HH;
    unsigned short* Vt   = Vh + (size_t)NTOK * HH;
    unsigned short* ctxb = Vt + (size_t)NTOK * HH;
    float* biasb = (float*)(ctxb + (size_t)NTOK * HH);
    int*   idxb  = (int*)(biasb + (size_t)NB * SS);
    int*   cntb  = idxb + (size_t)NB * SS;

    dim3 blk(256);

    prep<<<dim3(3074), blk, 0, stream>>>(hs, mask, Wq, Wk, Wv, Wo,
                                         Ab, Wt, idxb, biasb, cntb);

    gemm_qkv<<<dim3(24, 32), dim3(128), 0, stream>>>(Ab, Wt, bq, bk, bv, Qh);

    vtrans<<<dim3(SS / 64, NB * NHEAD), blk, 0, stream>>>(Vh, idxb, Vt);

    attn_mfma<<<dim3(512), blk, 0, stream>>>(Qh, Kh, Vt, biasb, idxb, cntb, ctxb);

    gemm_out<<<dim3(16, 32), blk, 0, stream>>>(ctxb, Wt + 3 * (size_t)HH * HH,
                                               bo, out);
}

// Round 19
// 96.818 us; speedup vs baseline: 1.2034x; 1.2034x over previous
//
#include <hip/hip_runtime.h>
#include <hip/hip_bf16.h>
#include <math.h>

#define NB 2
#define SS 2048
#define HH 1024
#define NHEAD 16
#define HDIM 64
#define NTOK (NB * SS)  // 4096

#define QSCALE 0.18033688011112042f   // 0.125 * log2(e)

typedef __attribute__((ext_vector_type(8))) short short8;
typedef __attribute__((ext_vector_type(4))) float f32x4;
typedef __attribute__((ext_vector_type(16))) float f32x16;

// byte-offset swizzles: XOR 16B-chunk index with low row bits
#define SWZ16(row, boff) ((boff) ^ (((row) & 7) << 4))    // 128B rows (8 chunks)
#define VSWZ(row, boff)  ((boff) ^ (((row) & 15) << 4))   // 256B rows (16 chunks)

// f32 -> bf16 round-to-nearest-even
__device__ __forceinline__ unsigned short f2b(float x) {
    union { float f; unsigned int u; } v; v.f = x;
    unsigned int u = v.u + 0x7fff + ((v.u >> 16) & 1);
    return (unsigned short)(u >> 16);
}

// pack two f32 -> one dword of 2 bf16 via HW instruction (T12)
__device__ __forceinline__ unsigned pk2a(float lo, float hi) {
    unsigned r;
    asm("v_cvt_pk_bf16_f32 %0, %1, %2" : "=v"(r) : "v"(lo), "v"(hi));
    return r;
}

__device__ __forceinline__ float exp2fast(float x) {
#if __has_builtin(__builtin_amdgcn_exp2f)
    return __builtin_amdgcn_exp2f(x);
#else
    return exp2f(x);
#endif
}

// async global->LDS, 16B per lane
__device__ __forceinline__ void gl16(const void* g, void* l) {
    __builtin_amdgcn_global_load_lds(
        (const __attribute__((address_space(1))) void*)g,
        (__attribute__((address_space(3))) void*)l, 16, 0, 0);
}

// ---------------------------------------------------------------------------
// Fused prep: blocks [0,2048) cvt_hs; [2048,3072) transpose_w; [3072,3074)
// mask_scan.
// ---------------------------------------------------------------------------
__global__ __launch_bounds__(256) void prep(
    const float* __restrict__ hs,
    const float* __restrict__ mask,
    const float* __restrict__ W0, const float* __restrict__ W1,
    const float* __restrict__ W2, const float* __restrict__ W3,
    unsigned short* __restrict__ Ab,
    unsigned short* __restrict__ Wt,
    int* __restrict__ idx, float* __restrict__ bias, int* __restrict__ cnt)
{
    __shared__ unsigned short T[64][72];
    __shared__ int part[256];
    const int bid = blockIdx.x;
    const int tid = threadIdx.x;

    if (bid < 2048) {
        const size_t i = ((size_t)bid * 256 + tid) * 8;
        float4 v0 = *(const float4*)(hs + i);
        float4 v1 = *(const float4*)(hs + i + 4);
        short8 o;
        o[0] = f2b(v0.x); o[1] = f2b(v0.y); o[2] = f2b(v0.z); o[3] = f2b(v0.w);
        o[4] = f2b(v1.x); o[5] = f2b(v1.y); o[6] = f2b(v1.z); o[7] = f2b(v1.w);
        *(short8*)(Ab + i) = o;
    } else if (bid < 3072) {
        const int t = bid - 2048;
        const int z = t >> 8;
        const int n0 = (t & 15) * 64, k0 = ((t >> 4) & 15) * 64;
        const float* W = z == 0 ? W0 : z == 1 ? W1 : z == 2 ? W2 : W3;
        unsigned short* dst = Wt + (size_t)z * HH * HH;
        {
            const int r = tid >> 2, c4 = (tid & 3) * 16;
            const float* src = W + (size_t)(k0 + r) * HH + n0 + c4;
#pragma unroll
            for (int j = 0; j < 16; j += 4) {
                float4 v = *(const float4*)(src + j);
                T[c4 + j + 0][r] = f2b(v.x); T[c4 + j + 1][r] = f2b(v.y);
                T[c4 + j + 2][r] = f2b(v.z); T[c4 + j + 3][r] = f2b(v.w);
            }
        }
        __syncthreads();
        {
            const int n = tid >> 2, sc = (tid & 3) * 2;
#pragma unroll
            for (int u = 0; u < 2; ++u) {
                short8 v = *(const short8*)&T[n][(sc + u) * 8];
                *(short8*)(dst + (size_t)(n0 + n) * HH + k0 + (sc + u) * 8) = v;
            }
        }
    } else {
        const int b = bid - 3072;
        int loc[8]; int m = 0;
        const float* mp = mask + (size_t)b * SS + tid * 8;
#pragma unroll
        for (int j = 0; j < 8; ++j) { loc[j] = (mp[j] == 0.0f) ? 1 : 0; m += loc[j]; }
        part[tid] = m;
        __syncthreads();
        for (int d = 1; d < 256; d <<= 1) {
            int v = (tid >= d) ? part[tid - d] : 0;
            __syncthreads();
            part[tid] += v;
            __syncthreads();
        }
        int base = part[tid] - m;
        const int total = part[255];
#pragma unroll
        for (int j = 0; j < 8; ++j)
            if (loc[j]) idx[(size_t)b * SS + (base++)] = tid * 8 + j;
        if (tid == 0) cnt[b] = total;
        __syncthreads();
        for (int j = tid; j < SS; j += 256) {
            if (j >= total) idx[(size_t)b * SS + j] = 0;
            bias[(size_t)b * SS + j] = (j < total) ? 0.0f : -1e30f;
        }
    }
}

// ---------------------------------------------------------------------------
// QKV GEMM: BK=32 double-buffered, counted vmcnt(4), raw s_barrier.
// 256 threads, 4 waves. Grid 768 = 3 blocks/CU (R13/R17 proven config).
// ---------------------------------------------------------------------------
__global__ __launch_bounds__(256) void gemm_qkv(
    const unsigned short* __restrict__ A, const unsigned short* __restrict__ Bt,
    const float* __restrict__ b0, const float* __restrict__ b1,
    const float* __restrict__ b2, unsigned short* __restrict__ Cout)
{
    __shared__ __align__(16) unsigned short As[2][128 * 32];
    __shared__ __align__(16) unsigned short Bs[2][128 * 32];

    const int tid = threadIdx.x;
    const int w  = tid >> 6;
    const int l  = tid & 63;
    const int g  = l >> 4, c = l & 15;
    const int wr = w >> 1, wc = w & 1;
    const int m0 = blockIdx.y * 128, n0 = blockIdx.x * 128;

    const int srow = l >> 2;
    const int gch  = (l & 3) ^ (srow & 3);

    f32x4 acc[4][4];
#pragma unroll
    for (int mi = 0; mi < 4; ++mi)
#pragma unroll
        for (int ni = 0; ni < 4; ++ni)
            acc[mi][ni] = (f32x4){0.f, 0.f, 0.f, 0.f};

#define STAGE(kt_, bb) {                                                      \
    _Pragma("unroll")                                                         \
    for (int u_ = 0; u_ < 2; ++u_) {                                          \
        const int rb_ = (w * 2 + u_) * 16;                                    \
        gl16(A  + (size_t)(m0 + rb_ + srow) * HH + (kt_) * 32 + gch * 8,      \
             (void*)&As[bb][rb_ * 32]);                                       \
        gl16(Bt + (size_t)(n0 + rb_ + srow) * HH + (kt_) * 32 + gch * 8,      \
             (void*)&Bs[bb][rb_ * 32]);                                       \
    } }

    STAGE(0, 0);
    STAGE(1, 1);

    for (int kt = 0; kt < 32; ++kt) {
        const int cb = kt & 1;
        if (kt < 31) asm volatile("s_waitcnt vmcnt(4)" ::: "memory");
        else         asm volatile("s_waitcnt vmcnt(0)" ::: "memory");
        __builtin_amdgcn_s_barrier();
        __builtin_amdgcn_sched_barrier(0);

        short8 af[4], bf[4];
#pragma unroll
        for (int mi = 0; mi < 4; ++mi) {
            const int row = wr * 64 + mi * 16 + c;
            af[mi] = *(const short8*)&As[cb][row * 32 + ((g * 8) ^ ((c & 3) * 8))];
        }
#pragma unroll
        for (int ni = 0; ni < 4; ++ni) {
            const int row = wc * 64 + ni * 16 + c;
            bf[ni] = *(const short8*)&Bs[cb][row * 32 + ((g * 8) ^ ((c & 3) * 8))];
        }
        __builtin_amdgcn_s_setprio(1);
#pragma unroll
        for (int mi = 0; mi < 4; ++mi)
#pragma unroll
            for (int ni = 0; ni < 4; ++ni)
                acc[mi][ni] = __builtin_amdgcn_mfma_f32_16x16x32_bf16(
                    af[mi], bf[ni], acc[mi][ni], 0, 0, 0);
        __builtin_amdgcn_s_setprio(0);

        __builtin_amdgcn_sched_barrier(0);
        __builtin_amdgcn_s_barrier();
        __builtin_amdgcn_sched_barrier(0);
        if (kt + 2 < 32) STAGE(kt + 2, cb);
    }
#undef STAGE

    const int which = n0 >> 10;
    const float* bp = which == 0 ? b0 : which == 1 ? b1 : b2;
    const float scl = which == 0 ? QSCALE : 1.0f;
    unsigned short* dst = Cout + (size_t)which * NTOK * HH;
#pragma unroll
    for (int ni = 0; ni < 4; ++ni) {
        const int nl = (n0 + wc * 64 + ni * 16 + c) & 1023;
        const int h = nl >> 6, d = nl & 63;
        const float bv = bp[nl];
#pragma unroll
        for (int mi = 0; mi < 4; ++mi) {
            const int mBase = m0 + wr * 64 + mi * 16 + g * 4;
#pragma unroll
            for (int j = 0; j < 4; ++j) {
                const int m = mBase + j;
                const int b = m >> 11, si = m & 2047;
                dst[(((size_t)(b * 16 + h)) * SS + si) * 64 + d] =
                    f2b((acc[mi][ni][j] + bv) * scl);
            }
        }
    }
}

// ---------------------------------------------------------------------------
// Out-proj GEMM: 128(M)x64(N) tiles, BK=64 dbuf, counted vmcnt(6).
// Grid (16,32) = 512 blocks -> 2 blocks/CU.
// ---------------------------------------------------------------------------
__global__ __launch_bounds__(256) void gemm_out(
    const unsigned short* __restrict__ A, const unsigned short* __restrict__ Bt,
    const float* __restrict__ b0, float* __restrict__ Cout)
{
    __shared__ __align__(16) unsigned short As[2][128 * 64];
    __shared__ __align__(16) unsigned short Bs[2][64 * 64];

    const int tid = threadIdx.x;
    const int w  = tid >> 6;
    const int l  = tid & 63;
    const int g  = l >> 4, c = l & 15;
    const int wr = w >> 1, wc = w & 1;
    const int m0 = blockIdx.y * 128, n0 = blockIdx.x * 64;

    const int dr = l >> 3;
    const int gc = (l & 7) ^ dr;

    const unsigned short* aBase = A  + (size_t)(m0 + w * 32 + dr) * HH + gc * 8;

    f32x4 acc[4][2];
#pragma unroll
    for (int mi = 0; mi < 4; ++mi)
#pragma unroll
        for (int ni = 0; ni < 2; ++ni)
            acc[mi][ni] = (f32x4){0.f, 0.f, 0.f, 0.f};

    const int swz = (c & 7) * 8;

#define STAGE(kt_, bb) {                                                      \
    const int koff = (kt_) * 64;                                              \
    _Pragma("unroll")                                                         \
    for (int i_ = 0; i_ < 4; ++i_)                                            \
        gl16(aBase + koff + (size_t)i_ * 8 * HH, (void*)&As[bb][(w*4+i_)*512]); \
    _Pragma("unroll")                                                         \
    for (int u_ = 0; u_ < 2; ++u_) {                                          \
        const int rb_ = (w * 2 + u_) * 8;                                     \
        gl16(Bt + (size_t)(n0 + rb_ + dr) * HH + koff + gc * 8,               \
             (void*)&Bs[bb][rb_ * 64]);                                       \
    } }

    STAGE(0, 0);
    STAGE(1, 1);

    for (int kt = 0; kt < 16; ++kt) {
        const int cb = kt & 1;
        if (kt < 15) asm volatile("s_waitcnt vmcnt(6)" ::: "memory");
        else         asm volatile("s_waitcnt vmcnt(0)" ::: "memory");
        __builtin_amdgcn_s_barrier();
        __builtin_amdgcn_sched_barrier(0);

        short8 af[2][4], bf[2][2];
#pragma unroll
        for (int ks = 0; ks < 2; ++ks) {
            const int kb = ks * 32;
#pragma unroll
            for (int mi = 0; mi < 4; ++mi) {
                const int row = wr * 64 + mi * 16 + c;
                af[ks][mi] = *(const short8*)&As[cb][row * 64 + ((kb + g * 8) ^ swz)];
            }
#pragma unroll
            for (int ni = 0; ni < 2; ++ni) {
                const int row = wc * 32 + ni * 16 + c;
                bf[ks][ni] = *(const short8*)&Bs[cb][row * 64 + ((kb + g * 8) ^ swz)];
            }
        }
        __builtin_amdgcn_s_setprio(1);
#pragma unroll
        for (int ks = 0; ks < 2; ++ks)
#pragma unroll
            for (int mi = 0; mi < 4; ++mi)
#pragma unroll
                for (int ni = 0; ni < 2; ++ni)
                    acc[mi][ni] = __builtin_amdgcn_mfma_f32_16x16x32_bf16(
                        af[ks][mi], bf[ks][ni], acc[mi][ni], 0, 0, 0);
        __builtin_amdgcn_s_setprio(0);

        __builtin_amdgcn_sched_barrier(0);
        __builtin_amdgcn_s_barrier();
        __builtin_amdgcn_sched_barrier(0);
        if (kt + 2 < 16) STAGE(kt + 2, cb);
    }
#undef STAGE

#pragma unroll
    for (int ni = 0; ni < 2; ++ni) {
        const int n = n0 + wc * 32 + ni * 16 + c;
        const float bv = b0[n];
#pragma unroll
        for (int mi = 0; mi < 4; ++mi) {
            const int mBase = m0 + wr * 64 + mi * 16 + g * 4;
#pragma unroll
            for (int j = 0; j < 4; ++j)
                Cout[(size_t)(mBase + j) * HH + n] = acc[mi][ni][j] + bv;
        }
    }
}

// ---------------------------------------------------------------------------
// V head-major [bh][s][64] -> Vt [bh][64][j] GATHERED along unmasked idx
// ---------------------------------------------------------------------------
__global__ __launch_bounds__(256) void vtrans(
    const unsigned short* __restrict__ Vh, const int* __restrict__ idx,
    unsigned short* __restrict__ Vt)
{
    __shared__ unsigned short T[64][72];
    const int tid = threadIdx.x;
    const int bh = blockIdx.y;
    const int b  = bh >> 4;
    const int s0 = blockIdx.x * 64;
    {
        const int r = tid >> 2, dc = (tid & 3) * 16;
        const int sidx = idx[(size_t)b * SS + s0 + r];
        const unsigned short* src = Vh + ((size_t)bh * SS + sidx) * 64 + dc;
        short8 v0 = *(const short8*)src;
        short8 v1 = *(const short8*)(src + 8);
#pragma unroll
        for (int j = 0; j < 8; ++j) {
            T[dc + j][r]     = (unsigned short)v0[j];
            T[dc + 8 + j][r] = (unsigned short)v1[j];
        }
    }
    __syncthreads();
    {
        const int d = tid >> 2, sc = (tid & 3) * 2;
#pragma unroll
        for (int u = 0; u < 2; ++u) {
            short8 v = *(const short8*)&T[d][(sc + u) * 8];
            *(short8*)(Vt + ((size_t)bh * 64 + d) * SS + s0 + (sc + u) * 8) = v;
        }
    }
}

// ---------------------------------------------------------------------------
// Flash attention over COMPACTED keys (exact). Swapped-QK^T 32x32x16,
// no-max log2 softmax, 4 waves x 32q = 128 q/block. 128-KEY double-buffered
// tiles, reg-staged prefetch (T14), K gathered via idx at stage time.
// Bias only on boundary tile. LDS 64KB -> 2 blocks/CU. Grid 512, XCD T1.
// ---------------------------------------------------------------------------
__global__ __launch_bounds__(256) void attn_mfma(
    const unsigned short* __restrict__ Qb, const unsigned short* __restrict__ Kb,
    const unsigned short* __restrict__ Vtb, const float* __restrict__ biasg,
    const int* __restrict__ idxg, const int* __restrict__ cntg,
    unsigned short* __restrict__ ctx)
{
    __shared__ __align__(16) unsigned short Ks[2][128 * 64];   // [key][d] 128B rows
    __shared__ __align__(16) unsigned short Vts[2][64 * 128];  // [d][key] 256B rows
    __shared__ float Sc[4][32];

    const int wg  = blockIdx.x;
    const int swg = (wg & 7) * 64 + (wg >> 3);
    const int qx  = swg & 15;
    const int bh  = swg >> 4;

    const int tid = threadIdx.x;
    const int l   = tid & 63;
    const int wq  = tid >> 6;
    const int hi  = l >> 5;
    const int c   = l & 31;
    const int b   = bh >> 4, h = bh & 15;
    const int q0  = qx * 128 + wq * 32;

    const unsigned short* Qp = Qb  + (size_t)bh * SS * 64;
    const unsigned short* Kp = Kb  + (size_t)bh * SS * 64;
    const unsigned short* Vp = Vtb + (size_t)bh * 64 * SS;
    const float* biasp = biasg + (size_t)b * SS;
    const int* idxb = idxg + (size_t)b * SS;

    const int cnt    = cntg[b];
    const int nt     = (cnt + 127) >> 7;   // 128-key tiles (<= 16)
    const int ntFull = cnt >> 7;           // fully-real tiles

    // staging maps
    const int sr  = tid >> 3;        // K rows: sr + 32u, u=0..3
    const int sc8 = tid & 7;         // K 16B chunk (of 8)
    const int vd  = tid >> 2;        // V^T row (d) 0..63
    const int vc0 = (tid & 3) * 4;   // V 16B chunks vc0+u (of 16)

    short8 qf[4];
    {
        const unsigned short* qrow = Qp + (size_t)(q0 + c) * 64 + hi * 8;
#pragma unroll
        for (int s = 0; s < 4; ++s) qf[s] = *(const short8*)(qrow + s * 16);
    }

    f32x16 oacc[2];
#pragma unroll
    for (int dt = 0; dt < 2; ++dt)
#pragma unroll
        for (int r = 0; r < 16; ++r) oacc[dt][r] = 0.f;

    float ls[4] = {0.f, 0.f, 0.f, 0.f};

    short8 kr0, kr1, kr2, kr3, vr0, vr1, vr2, vr3;

#define LOADREG(t_) {                                                         \
    const int* ip_ = idxb + (t_) * 128;                                       \
    kr0 = *(const short8*)(Kp + (size_t)ip_[sr      ] * 64 + sc8 * 8);        \
    kr1 = *(const short8*)(Kp + (size_t)ip_[sr + 32 ] * 64 + sc8 * 8);        \
    kr2 = *(const short8*)(Kp + (size_t)ip_[sr + 64 ] * 64 + sc8 * 8);        \
    kr3 = *(const short8*)(Kp + (size_t)ip_[sr + 96 ] * 64 + sc8 * 8);        \
    const unsigned short* vp_ = Vp + (size_t)vd * SS + (t_) * 128;            \
    vr0 = *(const short8*)(vp_ + (vc0 + 0) * 8);                              \
    vr1 = *(const short8*)(vp_ + (vc0 + 1) * 8);                              \
    vr2 = *(const short8*)(vp_ + (vc0 + 2) * 8);                              \
    vr3 = *(const short8*)(vp_ + (vc0 + 3) * 8); }

#define DSWRITE(bb) {                                                         \
    *(short8*)((char*)Ks[bb] + (sr      ) * 128 + SWZ16(sr,      sc8 * 16)) = kr0; \
    *(short8*)((char*)Ks[bb] + (sr + 32 ) * 128 + SWZ16(sr + 32, sc8 * 16)) = kr1; \
    *(short8*)((char*)Ks[bb] + (sr + 64 ) * 128 + SWZ16(sr + 64, sc8 * 16)) = kr2; \
    *(short8*)((char*)Ks[bb] + (sr + 96 ) * 128 + SWZ16(sr + 96, sc8 * 16)) = kr3; \
    *(short8*)((char*)Vts[bb] + vd * 256 + VSWZ(vd, (vc0 + 0) * 16)) = vr0;   \
    *(short8*)((char*)Vts[bb] + vd * 256 + VSWZ(vd, (vc0 + 1) * 16)) = vr1;   \
    *(short8*)((char*)Vts[bb] + vd * 256 + VSWZ(vd, (vc0 + 2) * 16)) = vr2;   \
    *(short8*)((char*)Vts[bb] + vd * 256 + VSWZ(vd, (vc0 + 3) * 16)) = vr3; }

    LOADREG(0);
    DSWRITE(0);
    __syncthreads();

    for (int t = 0; t < nt; ++t) {
        const int cb = t & 1;
        if (t + 1 < nt) LOADREG(t + 1);   // in flight during compute
        const bool needBias = (t >= ntFull);

#pragma unroll
        for (int hh = 0; hh < 4; ++hh) {   // four 32-key halves
            f32x16 s4h;
#pragma unroll
            for (int r = 0; r < 16; ++r) s4h[r] = 0.f;
            const int krow = hh * 32 + c;
            __builtin_amdgcn_s_setprio(1);
#pragma unroll
            for (int ss = 0; ss < 4; ++ss) {
                short8 kf = *(const short8*)((char*)Ks[cb] + krow * 128 +
                                             SWZ16(krow, (ss * 2 + hi) * 16));
                s4h = __builtin_amdgcn_mfma_f32_32x32x16_bf16(kf, qf[ss], s4h, 0, 0, 0);
            }
            __builtin_amdgcn_s_setprio(0);

            float pvv[16];
            if (needBias) {
                f32x4 mqh[4];
#pragma unroll
                for (int tt = 0; tt < 4; ++tt)
                    mqh[tt] = *(const f32x4*)(biasp + t * 128 + hh * 32 + tt * 8 + hi * 4);
#pragma unroll
                for (int r = 0; r < 16; ++r)
                    pvv[r] = exp2fast(s4h[r] + mqh[r >> 2][r & 3]);
            } else {
#pragma unroll
                for (int r = 0; r < 16; ++r)
                    pvv[r] = exp2fast(s4h[r]);
            }
#pragma unroll
            for (int r = 0; r < 16; ++r) ls[r & 3] += pvv[r];

            unsigned wdh[8];
#pragma unroll
            for (int j = 0; j < 8; ++j) wdh[j] = pk2a(pvv[2 * j], pvv[2 * j + 1]);
#pragma unroll
            for (int g4 = 0; g4 < 2; ++g4) {
                asm volatile("v_permlane32_swap_b32 %0, %1"
                             : "+v"(wdh[4 * g4 + 0]), "+v"(wdh[4 * g4 + 2]));
                asm volatile("v_permlane32_swap_b32 %0, %1"
                             : "+v"(wdh[4 * g4 + 1]), "+v"(wdh[4 * g4 + 3]));
            }

            __builtin_amdgcn_s_setprio(1);
#pragma unroll
            for (int s2 = 0; s2 < 2; ++s2) {
                const int vchunk = hh * 4 + s2 * 2 + hi;   // 16-key slice (of 16)
                union { unsigned u[4]; short8 s8; } pa;
#pragma unroll
                for (int u_ = 0; u_ < 4; ++u_) pa.u[u_] = wdh[4 * s2 + u_];
#pragma unroll
                for (int dt = 0; dt < 2; ++dt) {
                    const int vrow = dt * 32 + c;
                    short8 vf = *(const short8*)((char*)Vts[cb] + vrow * 256 +
                                                 VSWZ(vrow, vchunk * 16));
                    oacc[dt] = __builtin_amdgcn_mfma_f32_32x32x16_bf16(pa.s8, vf, oacc[dt], 0, 0, 0);
                }
            }
            __builtin_amdgcn_s_setprio(0);
        }

        if (t + 1 < nt) DSWRITE(cb ^ 1);   // buffer not being read this iter
        __syncthreads();                   // writes visible; all reads of cb done
    }
#undef LOADREG
#undef DSWRITE

    // ---- epilogue: per-wave l reduce + broadcast to D-row layout ----
    float lsum = (ls[0] + ls[1]) + (ls[2] + ls[3]);
    lsum += __shfl_xor(lsum, 32, 64);

    Sc[wq][c] = lsum;
    asm volatile("s_waitcnt lgkmcnt(0)" ::: "memory");
    f32x4 lq[4];
#pragma unroll
    for (int tt = 0; tt < 4; ++tt)
        lq[tt] = *(const f32x4*)&Sc[wq][tt * 8 + hi * 4];

#pragma unroll
    for (int dt = 0; dt < 2; ++dt)
#pragma unroll
        for (int r = 0; r < 16; ++r) {
            const int row = (r & 3) + 8 * (r >> 2) + 4 * hi;
            const float val = oacc[dt][r] / lq[r >> 2][r & 3];
            ctx[((size_t)(b * SS + q0 + row)) * HH + h * 64 + dt * 32 + c] = f2b(val);
        }
}

// ---------------------------------------------------------------------------
extern "C" void kernel_launch(void* const* d_in, const int* in_sizes, int n_in,
                              void* d_out, int out_size, void* d_ws, size_t ws_size,
                              hipStream_t stream)
{
    const float* hs   = (const float*)d_in[0];
    const float* mask = (const float*)d_in[1];
    const float* Wq   = (const float*)d_in[2];
    const float* bq   = (const float*)d_in[3];
    const float* Wk   = (const float*)d_in[4];
    const float* bk   = (const float*)d_in[5];
    const float* Wv   = (const float*)d_in[6];
    const float* bv   = (const float*)d_in[7];
    const float* Wo   = (const float*)d_in[8];
    const float* bo   = (const float*)d_in[9];
    float* out = (float*)d_out;

    unsigned short* Ab   = (unsigned short*)d_ws;
    unsigned short* Wt   = Ab + (size_t)NTOK * HH;
    unsigned short* Qh   = Wt + (size_t)4 * HH * HH;   // Qh|Kh|Vh contiguous
    unsigned short* Kh   = Qh + (size_t)NTOK * HH;
    unsigned short* Vh   = Kh + (size_t)NTOK * HH;
    unsigned short* Vt   = Vh + (size_t)NTOK * HH;
    unsigned short* ctxb = Vt + (size_t)NTOK * HH;
    float* biasb = (float*)(ctxb + (size_t)NTOK * HH);
    int*   idxb  = (int*)(biasb + (size_t)NB * SS);
    int*   cntb  = idxb + (size_t)NB * SS;

    dim3 blk(256);

    prep<<<dim3(3074), blk, 0, stream>>>(hs, mask, Wq, Wk, Wv, Wo,
                                         Ab, Wt, idxb, biasb, cntb);

    gemm_qkv<<<dim3(24, 32), blk, 0, stream>>>(Ab, Wt, bq, bk, bv, Qh);

    vtrans<<<dim3(SS / 64, NB * NHEAD), blk, 0, stream>>>(Vh, idxb, Vt);

    attn_mfma<<<dim3(512), blk, 0, stream>>>(Qh, Kh, Vt, biasb, idxb, cntb, ctxb);

    gemm_out<<<dim3(16, 32), blk, 0, stream>>>(ctxb, Wt + 3 * (size_t)HH * HH,
                                               bo, out);
}

// Round 20
// 96.253 us; speedup vs baseline: 1.2104x; 1.0059x over previous
//
#include <hip/hip_runtime.h>
#include <hip/hip_bf16.h>
#include <math.h>

#define NB 2
#define SS 2048
#define HH 1024
#define NHEAD 16
#define HDIM 64
#define NTOK (NB * SS)  // 4096

#define QSCALE 0.18033688011112042f   // 0.125 * log2(e)

typedef __attribute__((ext_vector_type(8))) short short8;
typedef __attribute__((ext_vector_type(4))) float f32x4;
typedef __attribute__((ext_vector_type(16))) float f32x16;

// byte-offset swizzles: XOR 16B-chunk index with low row bits
#define SWZ16(row, boff) ((boff) ^ (((row) & 7) << 4))    // 128B rows (8 chunks)
#define VSWZ(row, boff)  ((boff) ^ (((row) & 15) << 4))   // 256B rows (16 chunks)

// f32 -> bf16 round-to-nearest-even
__device__ __forceinline__ unsigned short f2b(float x) {
    union { float f; unsigned int u; } v; v.f = x;
    unsigned int u = v.u + 0x7fff + ((v.u >> 16) & 1);
    return (unsigned short)(u >> 16);
}

// pack two f32 -> one dword of 2 bf16 via HW instruction (T12)
__device__ __forceinline__ unsigned pk2a(float lo, float hi) {
    unsigned r;
    asm("v_cvt_pk_bf16_f32 %0, %1, %2" : "=v"(r) : "v"(lo), "v"(hi));
    return r;
}

__device__ __forceinline__ float exp2fast(float x) {
#if __has_builtin(__builtin_amdgcn_exp2f)
    return __builtin_amdgcn_exp2f(x);
#else
    return exp2f(x);
#endif
}

// async global->LDS, 16B per lane
__device__ __forceinline__ void gl16(const void* g, void* l) {
    __builtin_amdgcn_global_load_lds(
        (const __attribute__((address_space(1))) void*)g,
        (__attribute__((address_space(3))) void*)l, 16, 0, 0);
}

// ---------------------------------------------------------------------------
// Fused prep: blocks [0,2048) cvt_hs; [2048,3072) transpose_w; [3072,3074)
// mask_scan.
// ---------------------------------------------------------------------------
__global__ __launch_bounds__(256) void prep(
    const float* __restrict__ hs,
    const float* __restrict__ mask,
    const float* __restrict__ W0, const float* __restrict__ W1,
    const float* __restrict__ W2, const float* __restrict__ W3,
    unsigned short* __restrict__ Ab,
    unsigned short* __restrict__ Wt,
    int* __restrict__ idx, float* __restrict__ bias, int* __restrict__ cnt)
{
    __shared__ unsigned short T[64][72];
    __shared__ int part[256];
    const int bid = blockIdx.x;
    const int tid = threadIdx.x;

    if (bid < 2048) {
        const size_t i = ((size_t)bid * 256 + tid) * 8;
        float4 v0 = *(const float4*)(hs + i);
        float4 v1 = *(const float4*)(hs + i + 4);
        short8 o;
        o[0] = f2b(v0.x); o[1] = f2b(v0.y); o[2] = f2b(v0.z); o[3] = f2b(v0.w);
        o[4] = f2b(v1.x); o[5] = f2b(v1.y); o[6] = f2b(v1.z); o[7] = f2b(v1.w);
        *(short8*)(Ab + i) = o;
    } else if (bid < 3072) {
        const int t = bid - 2048;
        const int z = t >> 8;
        const int n0 = (t & 15) * 64, k0 = ((t >> 4) & 15) * 64;
        const float* W = z == 0 ? W0 : z == 1 ? W1 : z == 2 ? W2 : W3;
        unsigned short* dst = Wt + (size_t)z * HH * HH;
        {
            const int r = tid >> 2, c4 = (tid & 3) * 16;
            const float* src = W + (size_t)(k0 + r) * HH + n0 + c4;
#pragma unroll
            for (int j = 0; j < 16; j += 4) {
                float4 v = *(const float4*)(src + j);
                T[c4 + j + 0][r] = f2b(v.x); T[c4 + j + 1][r] = f2b(v.y);
                T[c4 + j + 2][r] = f2b(v.z); T[c4 + j + 3][r] = f2b(v.w);
            }
        }
        __syncthreads();
        {
            const int n = tid >> 2, sc = (tid & 3) * 2;
#pragma unroll
            for (int u = 0; u < 2; ++u) {
                short8 v = *(const short8*)&T[n][(sc + u) * 8];
                *(short8*)(dst + (size_t)(n0 + n) * HH + k0 + (sc + u) * 8) = v;
            }
        }
    } else {
        const int b = bid - 3072;
        int loc[8]; int m = 0;
        const float* mp = mask + (size_t)b * SS + tid * 8;
#pragma unroll
        for (int j = 0; j < 8; ++j) { loc[j] = (mp[j] == 0.0f) ? 1 : 0; m += loc[j]; }
        part[tid] = m;
        __syncthreads();
        for (int d = 1; d < 256; d <<= 1) {
            int v = (tid >= d) ? part[tid - d] : 0;
            __syncthreads();
            part[tid] += v;
            __syncthreads();
        }
        int base = part[tid] - m;
        const int total = part[255];
#pragma unroll
        for (int j = 0; j < 8; ++j)
            if (loc[j]) idx[(size_t)b * SS + (base++)] = tid * 8 + j;
        if (tid == 0) cnt[b] = total;
        __syncthreads();
        for (int j = tid; j < SS; j += 256) {
            if (j >= total) idx[(size_t)b * SS + j] = 0;
            bias[(size_t)b * SS + j] = (j < total) ? 0.0f : -1e30f;
        }
    }
}

// ---------------------------------------------------------------------------
// QKV GEMM: BK=32 double-buffered, counted vmcnt(4), raw s_barrier.
// Flat grid 768 with XCD-chunked swizzle (T1): each XCD owns 96 contiguous
// logical tiles -> A-row/B-col panel reuse stays in one L2.
// ---------------------------------------------------------------------------
__global__ __launch_bounds__(256) void gemm_qkv(
    const unsigned short* __restrict__ A, const unsigned short* __restrict__ Bt,
    const float* __restrict__ b0, const float* __restrict__ b1,
    const float* __restrict__ b2, unsigned short* __restrict__ Cout)
{
    __shared__ __align__(16) unsigned short As[2][128 * 32];
    __shared__ __align__(16) unsigned short Bs[2][128 * 32];

    // XCD swizzle: 768 blocks, 8 XCDs -> 96-tile contiguous chunks
    const int f    = blockIdx.x;
    const int wgid = (f & 7) * 96 + (f >> 3);
    const int bx   = wgid % 24;     // n-tile (24)
    const int by   = wgid / 24;     // m-tile (32)

    const int tid = threadIdx.x;
    const int w  = tid >> 6;
    const int l  = tid & 63;
    const int g  = l >> 4, c = l & 15;
    const int wr = w >> 1, wc = w & 1;
    const int m0 = by * 128, n0 = bx * 128;

    const int srow = l >> 2;
    const int gch  = (l & 3) ^ (srow & 3);

    f32x4 acc[4][4];
#pragma unroll
    for (int mi = 0; mi < 4; ++mi)
#pragma unroll
        for (int ni = 0; ni < 4; ++ni)
            acc[mi][ni] = (f32x4){0.f, 0.f, 0.f, 0.f};

#define STAGE(kt_, bb) {                                                      \
    _Pragma("unroll")                                                         \
    for (int u_ = 0; u_ < 2; ++u_) {                                          \
        const int rb_ = (w * 2 + u_) * 16;                                    \
        gl16(A  + (size_t)(m0 + rb_ + srow) * HH + (kt_) * 32 + gch * 8,      \
             (void*)&As[bb][rb_ * 32]);                                       \
        gl16(Bt + (size_t)(n0 + rb_ + srow) * HH + (kt_) * 32 + gch * 8,      \
             (void*)&Bs[bb][rb_ * 32]);                                       \
    } }

    STAGE(0, 0);
    STAGE(1, 1);

    for (int kt = 0; kt < 32; ++kt) {
        const int cb = kt & 1;
        if (kt < 31) asm volatile("s_waitcnt vmcnt(4)" ::: "memory");
        else         asm volatile("s_waitcnt vmcnt(0)" ::: "memory");
        __builtin_amdgcn_s_barrier();
        __builtin_amdgcn_sched_barrier(0);

        short8 af[4], bf[4];
#pragma unroll
        for (int mi = 0; mi < 4; ++mi) {
            const int row = wr * 64 + mi * 16 + c;
            af[mi] = *(const short8*)&As[cb][row * 32 + ((g * 8) ^ ((c & 3) * 8))];
        }
#pragma unroll
        for (int ni = 0; ni < 4; ++ni) {
            const int row = wc * 64 + ni * 16 + c;
            bf[ni] = *(const short8*)&Bs[cb][row * 32 + ((g * 8) ^ ((c & 3) * 8))];
        }
        __builtin_amdgcn_s_setprio(1);
#pragma unroll
        for (int mi = 0; mi < 4; ++mi)
#pragma unroll
            for (int ni = 0; ni < 4; ++ni)
                acc[mi][ni] = __builtin_amdgcn_mfma_f32_16x16x32_bf16(
                    af[mi], bf[ni], acc[mi][ni], 0, 0, 0);
        __builtin_amdgcn_s_setprio(0);

        __builtin_amdgcn_sched_barrier(0);
        __builtin_amdgcn_s_barrier();
        __builtin_amdgcn_sched_barrier(0);
        if (kt + 2 < 32) STAGE(kt + 2, cb);
    }
#undef STAGE

    const int which = n0 >> 10;
    const float* bp = which == 0 ? b0 : which == 1 ? b1 : b2;
    const float scl = which == 0 ? QSCALE : 1.0f;
    unsigned short* dst = Cout + (size_t)which * NTOK * HH;
#pragma unroll
    for (int ni = 0; ni < 4; ++ni) {
        const int nl = (n0 + wc * 64 + ni * 16 + c) & 1023;
        const int h = nl >> 6, d = nl & 63;
        const float bv = bp[nl];
#pragma unroll
        for (int mi = 0; mi < 4; ++mi) {
            const int mBase = m0 + wr * 64 + mi * 16 + g * 4;
#pragma unroll
            for (int j = 0; j < 4; ++j) {
                const int m = mBase + j;
                const int b = m >> 11, si = m & 2047;
                dst[(((size_t)(b * 16 + h)) * SS + si) * 64 + d] =
                    f2b((acc[mi][ni][j] + bv) * scl);
            }
        }
    }
}

// ---------------------------------------------------------------------------
// Out-proj GEMM: 128(M)x64(N) tiles, BK=64 dbuf, counted vmcnt(6).
// Flat grid 512 with XCD-chunked swizzle (T1): 64-tile chunks per XCD.
// ---------------------------------------------------------------------------
__global__ __launch_bounds__(256) void gemm_out(
    const unsigned short* __restrict__ A, const unsigned short* __restrict__ Bt,
    const float* __restrict__ b0, float* __restrict__ Cout)
{
    __shared__ __align__(16) unsigned short As[2][128 * 64];
    __shared__ __align__(16) unsigned short Bs[2][64 * 64];

    // XCD swizzle: 512 blocks, 8 XCDs -> 64-tile contiguous chunks
    const int f    = blockIdx.x;
    const int wgid = (f & 7) * 64 + (f >> 3);
    const int bx   = wgid & 15;     // n-tile (16)
    const int by   = wgid >> 4;     // m-tile (32)

    const int tid = threadIdx.x;
    const int w  = tid >> 6;
    const int l  = tid & 63;
    const int g  = l >> 4, c = l & 15;
    const int wr = w >> 1, wc = w & 1;
    const int m0 = by * 128, n0 = bx * 64;

    const int dr = l >> 3;
    const int gc = (l & 7) ^ dr;

    const unsigned short* aBase = A  + (size_t)(m0 + w * 32 + dr) * HH + gc * 8;

    f32x4 acc[4][2];
#pragma unroll
    for (int mi = 0; mi < 4; ++mi)
#pragma unroll
        for (int ni = 0; ni < 2; ++ni)
            acc[mi][ni] = (f32x4){0.f, 0.f, 0.f, 0.f};

    const int swz = (c & 7) * 8;

#define STAGE(kt_, bb) {                                                      \
    const int koff = (kt_) * 64;                                              \
    _Pragma("unroll")                                                         \
    for (int i_ = 0; i_ < 4; ++i_)                                            \
        gl16(aBase + koff + (size_t)i_ * 8 * HH, (void*)&As[bb][(w*4+i_)*512]); \
    _Pragma("unroll")                                                         \
    for (int u_ = 0; u_ < 2; ++u_) {                                          \
        const int rb_ = (w * 2 + u_) * 8;                                     \
        gl16(Bt + (size_t)(n0 + rb_ + dr) * HH + koff + gc * 8,               \
             (void*)&Bs[bb][rb_ * 64]);                                       \
    } }

    STAGE(0, 0);
    STAGE(1, 1);

    for (int kt = 0; kt < 16; ++kt) {
        const int cb = kt & 1;
        if (kt < 15) asm volatile("s_waitcnt vmcnt(6)" ::: "memory");
        else         asm volatile("s_waitcnt vmcnt(0)" ::: "memory");
        __builtin_amdgcn_s_barrier();
        __builtin_amdgcn_sched_barrier(0);

        short8 af[2][4], bf[2][2];
#pragma unroll
        for (int ks = 0; ks < 2; ++ks) {
            const int kb = ks * 32;
#pragma unroll
            for (int mi = 0; mi < 4; ++mi) {
                const int row = wr * 64 + mi * 16 + c;
                af[ks][mi] = *(const short8*)&As[cb][row * 64 + ((kb + g * 8) ^ swz)];
            }
#pragma unroll
            for (int ni = 0; ni < 2; ++ni) {
                const int row = wc * 32 + ni * 16 + c;
                bf[ks][ni] = *(const short8*)&Bs[cb][row * 64 + ((kb + g * 8) ^ swz)];
            }
        }
        __builtin_amdgcn_s_setprio(1);
#pragma unroll
        for (int ks = 0; ks < 2; ++ks)
#pragma unroll
            for (int mi = 0; mi < 4; ++mi)
#pragma unroll
                for (int ni = 0; ni < 2; ++ni)
                    acc[mi][ni] = __builtin_amdgcn_mfma_f32_16x16x32_bf16(
                        af[ks][mi], bf[ks][ni], acc[mi][ni], 0, 0, 0);
        __builtin_amdgcn_s_setprio(0);

        __builtin_amdgcn_sched_barrier(0);
        __builtin_amdgcn_s_barrier();
        __builtin_amdgcn_sched_barrier(0);
        if (kt + 2 < 16) STAGE(kt + 2, cb);
    }
#undef STAGE

#pragma unroll
    for (int ni = 0; ni < 2; ++ni) {
        const int n = n0 + wc * 32 + ni * 16 + c;
        const float bv = b0[n];
#pragma unroll
        for (int mi = 0; mi < 4; ++mi) {
            const int mBase = m0 + wr * 64 + mi * 16 + g * 4;
#pragma unroll
            for (int j = 0; j < 4; ++j)
                Cout[(size_t)(mBase + j) * HH + n] = acc[mi][ni][j] + bv;
        }
    }
}

// ---------------------------------------------------------------------------
// V head-major [bh][s][64] -> Vt [bh][64][j] GATHERED along unmasked idx.
// Early-exit for key tiles beyond the padded compacted count (attn never
// reads Vt columns >= ceil(cnt/128)*128).
// ---------------------------------------------------------------------------
__global__ __launch_bounds__(256) void vtrans(
    const unsigned short* __restrict__ Vh, const int* __restrict__ idx,
    const int* __restrict__ cntg, unsigned short* __restrict__ Vt)
{
    __shared__ unsigned short T[64][72];
    const int tid = threadIdx.x;
    const int bh = blockIdx.y;
    const int b  = bh >> 4;
    const int s0 = blockIdx.x * 64;

    const int lim = ((cntg[b] + 127) >> 7) << 7;   // padded to 128-key tiles
    if (s0 >= lim) return;

    {
        const int r = tid >> 2, dc = (tid & 3) * 16;
        const int sidx = idx[(size_t)b * SS + s0 + r];
        const unsigned short* src = Vh + ((size_t)bh * SS + sidx) * 64 + dc;
        short8 v0 = *(const short8*)src;
        short8 v1 = *(const short8*)(src + 8);
#pragma unroll
        for (int j = 0; j < 8; ++j) {
            T[dc + j][r]     = (unsigned short)v0[j];
            T[dc + 8 + j][r] = (unsigned short)v1[j];
        }
    }
    __syncthreads();
    {
        const int d = tid >> 2, sc = (tid & 3) * 2;
#pragma unroll
        for (int u = 0; u < 2; ++u) {
            short8 v = *(const short8*)&T[d][(sc + u) * 8];
            *(short8*)(Vt + ((size_t)bh * 64 + d) * SS + s0 + (sc + u) * 8) = v;
        }
    }
}

// ---------------------------------------------------------------------------
// Flash attention over COMPACTED keys (exact). Swapped-QK^T 32x32x16,
// no-max log2 softmax, 4 waves x 32q = 128 q/block. 128-KEY double-buffered
// tiles, reg-staged prefetch (T14), K gathered via idx at stage time.
// Bias only on boundary tile. LDS 64KB -> 2 blocks/CU. Grid 512, XCD T1.
// ---------------------------------------------------------------------------
__global__ __launch_bounds__(256) void attn_mfma(
    const unsigned short* __restrict__ Qb, const unsigned short* __restrict__ Kb,
    const unsigned short* __restrict__ Vtb, const float* __restrict__ biasg,
    const int* __restrict__ idxg, const int* __restrict__ cntg,
    unsigned short* __restrict__ ctx)
{
    __shared__ __align__(16) unsigned short Ks[2][128 * 64];   // [key][d] 128B rows
    __shared__ __align__(16) unsigned short Vts[2][64 * 128];  // [d][key] 256B rows
    __shared__ float Sc[4][32];

    const int wg  = blockIdx.x;
    const int swg = (wg & 7) * 64 + (wg >> 3);
    const int qx  = swg & 15;
    const int bh  = swg >> 4;

    const int tid = threadIdx.x;
    const int l   = tid & 63;
    const int wq  = tid >> 6;
    const int hi  = l >> 5;
    const int c   = l & 31;
    const int b   = bh >> 4, h = bh & 15;
    const int q0  = qx * 128 + wq * 32;

    const unsigned short* Qp = Qb  + (size_t)bh * SS * 64;
    const unsigned short* Kp = Kb  + (size_t)bh * SS * 64;
    const unsigned short* Vp = Vtb + (size_t)bh * 64 * SS;
    const float* biasp = biasg + (size_t)b * SS;
    const int* idxb = idxg + (size_t)b * SS;

    const int cnt    = cntg[b];
    const int nt     = (cnt + 127) >> 7;   // 128-key tiles (<= 16)
    const int ntFull = cnt >> 7;           // fully-real tiles

    // staging maps
    const int sr  = tid >> 3;        // K rows: sr + 32u, u=0..3
    const int sc8 = tid & 7;         // K 16B chunk (of 8)
    const int vd  = tid >> 2;        // V^T row (d) 0..63
    const int vc0 = (tid & 3) * 4;   // V 16B chunks vc0+u (of 16)

    short8 qf[4];
    {
        const unsigned short* qrow = Qp + (size_t)(q0 + c) * 64 + hi * 8;
#pragma unroll
        for (int s = 0; s < 4; ++s) qf[s] = *(const short8*)(qrow + s * 16);
    }

    f32x16 oacc[2];
#pragma unroll
    for (int dt = 0; dt < 2; ++dt)
#pragma unroll
        for (int r = 0; r < 16; ++r) oacc[dt][r] = 0.f;

    float ls[4] = {0.f, 0.f, 0.f, 0.f};

    short8 kr0, kr1, kr2, kr3, vr0, vr1, vr2, vr3;

#define LOADREG(t_) {                                                         \
    const int* ip_ = idxb + (t_) * 128;                                       \
    kr0 = *(const short8*)(Kp + (size_t)ip_[sr      ] * 64 + sc8 * 8);        \
    kr1 = *(const short8*)(Kp + (size_t)ip_[sr + 32 ] * 64 + sc8 * 8);        \
    kr2 = *(const short8*)(Kp + (size_t)ip_[sr + 64 ] * 64 + sc8 * 8);        \
    kr3 = *(const short8*)(Kp + (size_t)ip_[sr + 96 ] * 64 + sc8 * 8);        \
    const unsigned short* vp_ = Vp + (size_t)vd * SS + (t_) * 128;            \
    vr0 = *(const short8*)(vp_ + (vc0 + 0) * 8);                              \
    vr1 = *(const short8*)(vp_ + (vc0 + 1) * 8);                              \
    vr2 = *(const short8*)(vp_ + (vc0 + 2) * 8);                              \
    vr3 = *(const short8*)(vp_ + (vc0 + 3) * 8); }

#define DSWRITE(bb) {                                                         \
    *(short8*)((char*)Ks[bb] + (sr      ) * 128 + SWZ16(sr,      sc8 * 16)) = kr0; \
    *(short8*)((char*)Ks[bb] + (sr + 32 ) * 128 + SWZ16(sr + 32, sc8 * 16)) = kr1; \
    *(short8*)((char*)Ks[bb] + (sr + 64 ) * 128 + SWZ16(sr + 64, sc8 * 16)) = kr2; \
    *(short8*)((char*)Ks[bb] + (sr + 96 ) * 128 + SWZ16(sr + 96, sc8 * 16)) = kr3; \
    *(short8*)((char*)Vts[bb] + vd * 256 + VSWZ(vd, (vc0 + 0) * 16)) = vr0;   \
    *(short8*)((char*)Vts[bb] + vd * 256 + VSWZ(vd, (vc0 + 1) * 16)) = vr1;   \
    *(short8*)((char*)Vts[bb] + vd * 256 + VSWZ(vd, (vc0 + 2) * 16)) = vr2;   \
    *(short8*)((char*)Vts[bb] + vd * 256 + VSWZ(vd, (vc0 + 3) * 16)) = vr3; }

    LOADREG(0);
    DSWRITE(0);
    __syncthreads();

    for (int t = 0; t < nt; ++t) {
        const int cb = t & 1;
        if (t + 1 < nt) LOADREG(t + 1);   // in flight during compute
        const bool needBias = (t >= ntFull);

#pragma unroll
        for (int hh = 0; hh < 4; ++hh) {   // four 32-key halves
            f32x16 s4h;
#pragma unroll
            for (int r = 0; r < 16; ++r) s4h[r] = 0.f;
            const int krow = hh * 32 + c;
            __builtin_amdgcn_s_setprio(1);
#pragma unroll
            for (int ss = 0; ss < 4; ++ss) {
                short8 kf = *(const short8*)((char*)Ks[cb] + krow * 128 +
                                             SWZ16(krow, (ss * 2 + hi) * 16));
                s4h = __builtin_amdgcn_mfma_f32_32x32x16_bf16(kf, qf[ss], s4h, 0, 0, 0);
            }
            __builtin_amdgcn_s_setprio(0);

            float pvv[16];
            if (needBias) {
                f32x4 mqh[4];
#pragma unroll
                for (int tt = 0; tt < 4; ++tt)
                    mqh[tt] = *(const f32x4*)(biasp + t * 128 + hh * 32 + tt * 8 + hi * 4);
#pragma unroll
                for (int r = 0; r < 16; ++r)
                    pvv[r] = exp2fast(s4h[r] + mqh[r >> 2][r & 3]);
            } else {
#pragma unroll
                for (int r = 0; r < 16; ++r)
                    pvv[r] = exp2fast(s4h[r]);
            }
#pragma unroll
            for (int r = 0; r < 16; ++r) ls[r & 3] += pvv[r];

            unsigned wdh[8];
#pragma unroll
            for (int j = 0; j < 8; ++j) wdh[j] = pk2a(pvv[2 * j], pvv[2 * j + 1]);
#pragma unroll
            for (int g4 = 0; g4 < 2; ++g4) {
                asm volatile("v_permlane32_swap_b32 %0, %1"
                             : "+v"(wdh[4 * g4 + 0]), "+v"(wdh[4 * g4 + 2]));
                asm volatile("v_permlane32_swap_b32 %0, %1"
                             : "+v"(wdh[4 * g4 + 1]), "+v"(wdh[4 * g4 + 3]));
            }

            __builtin_amdgcn_s_setprio(1);
#pragma unroll
            for (int s2 = 0; s2 < 2; ++s2) {
                const int vchunk = hh * 4 + s2 * 2 + hi;   // 16-key slice (of 16)
                union { unsigned u[4]; short8 s8; } pa;
#pragma unroll
                for (int u_ = 0; u_ < 4; ++u_) pa.u[u_] = wdh[4 * s2 + u_];
#pragma unroll
                for (int dt = 0; dt < 2; ++dt) {
                    const int vrow = dt * 32 + c;
                    short8 vf = *(const short8*)((char*)Vts[cb] + vrow * 256 +
                                                 VSWZ(vrow, vchunk * 16));
                    oacc[dt] = __builtin_amdgcn_mfma_f32_32x32x16_bf16(pa.s8, vf, oacc[dt], 0, 0, 0);
                }
            }
            __builtin_amdgcn_s_setprio(0);
        }

        if (t + 1 < nt) DSWRITE(cb ^ 1);   // buffer not being read this iter
        __syncthreads();                   // writes visible; all reads of cb done
    }
#undef LOADREG
#undef DSWRITE

    // ---- epilogue: per-wave l reduce + broadcast to D-row layout ----
    float lsum = (ls[0] + ls[1]) + (ls[2] + ls[3]);
    lsum += __shfl_xor(lsum, 32, 64);

    Sc[wq][c] = lsum;
    asm volatile("s_waitcnt lgkmcnt(0)" ::: "memory");
    f32x4 lq[4];
#pragma unroll
    for (int tt = 0; tt < 4; ++tt)
        lq[tt] = *(const f32x4*)&Sc[wq][tt * 8 + hi * 4];

#pragma unroll
    for (int dt = 0; dt < 2; ++dt)
#pragma unroll
        for (int r = 0; r < 16; ++r) {
            const int row = (r & 3) + 8 * (r >> 2) + 4 * hi;
            const float val = oacc[dt][r] / lq[r >> 2][r & 3];
            ctx[((size_t)(b * SS + q0 + row)) * HH + h * 64 + dt * 32 + c] = f2b(val);
        }
}

// ---------------------------------------------------------------------------
extern "C" void kernel_launch(void* const* d_in, const int* in_sizes, int n_in,
                              void* d_out, int out_size, void* d_ws, size_t ws_size,
                              hipStream_t stream)
{
    const float* hs   = (const float*)d_in[0];
    const float* mask = (const float*)d_in[1];
    const float* Wq   = (const float*)d_in[2];
    const float* bq   = (const float*)d_in[3];
    const float* Wk   = (const float*)d_in[4];
    const float* bk   = (const float*)d_in[5];
    const float* Wv   = (const float*)d_in[6];
    const float* bv   = (const float*)d_in[7];
    const float* Wo   = (const float*)d_in[8];
    const float* bo   = (const float*)d_in[9];
    float* out = (float*)d_out;

    unsigned short* Ab   = (unsigned short*)d_ws;
    unsigned short* Wt   = Ab + (size_t)NTOK * HH;
    unsigned short* Qh   = Wt + (size_t)4 * HH * HH;   // Qh|Kh|Vh contiguous
    unsigned short* Kh   = Qh + (size_t)NTOK * HH;
    unsigned short* Vh   = Kh + (size_t)NTOK * HH;
    unsigned short* Vt   = Vh + (size_t)NTOK * HH;
    unsigned short* ctxb = Vt + (size_t)NTOK * HH;
    float* biasb = (float*)(ctxb + (size_t)NTOK * HH);
    int*   idxb  = (int*)(biasb + (size_t)NB * SS);
    int*   cntb  = idxb + (size_t)NB * SS;

    dim3 blk(256);

    prep<<<dim3(3074), blk, 0, stream>>>(hs, mask, Wq, Wk, Wv, Wo,
                                         Ab, Wt, idxb, biasb, cntb);

    gemm_qkv<<<dim3(768), blk, 0, stream>>>(Ab, Wt, bq, bk, bv, Qh);

    vtrans<<<dim3(SS / 64, NB * NHEAD), blk, 0, stream>>>(Vh, idxb, cntb, Vt);

    attn_mfma<<<dim3(512), blk, 0, stream>>>(Qh, Kh, Vt, biasb, idxb, cntb, ctxb);

    gemm_out<<<dim3(512), blk, 0, stream>>>(ctxb, Wt + 3 * (size_t)HH * HH,
                                            bo, out);
}

// Round 21
// 94.649 us; speedup vs baseline: 1.2309x; 1.0169x over previous
//
#include <hip/hip_runtime.h>
#include <hip/hip_bf16.h>
#include <math.h>

#define NB 2
#define SS 2048
#define HH 1024
#define NHEAD 16
#define HDIM 64
#define NTOK (NB * SS)  // 4096

#define QSCALE 0.18033688011112042f   // 0.125 * log2(e)

typedef __attribute__((ext_vector_type(8))) short short8;
typedef __attribute__((ext_vector_type(4))) float f32x4;
typedef __attribute__((ext_vector_type(16))) float f32x16;

// byte-offset swizzles: XOR 16B-chunk index with low row bits
#define SWZ16(row, boff) ((boff) ^ (((row) & 7) << 4))    // 128B rows (8 chunks)
#define VSWZ(row, boff)  ((boff) ^ (((row) & 15) << 4))   // 256B rows (16 chunks)

// f32 -> bf16 round-to-nearest-even
__device__ __forceinline__ unsigned short f2b(float x) {
    union { float f; unsigned int u; } v; v.f = x;
    unsigned int u = v.u + 0x7fff + ((v.u >> 16) & 1);
    return (unsigned short)(u >> 16);
}

// pack two f32 -> one dword of 2 bf16 via HW instruction (T12)
__device__ __forceinline__ unsigned pk2a(float lo, float hi) {
    unsigned r;
    asm("v_cvt_pk_bf16_f32 %0, %1, %2" : "=v"(r) : "v"(lo), "v"(hi));
    return r;
}

__device__ __forceinline__ float exp2fast(float x) {
#if __has_builtin(__builtin_amdgcn_exp2f)
    return __builtin_amdgcn_exp2f(x);
#else
    return exp2f(x);
#endif
}

// async global->LDS, 16B per lane
__device__ __forceinline__ void gl16(const void* g, void* l) {
    __builtin_amdgcn_global_load_lds(
        (const __attribute__((address_space(1))) void*)g,
        (__attribute__((address_space(3))) void*)l, 16, 0, 0);
}

// ---------------------------------------------------------------------------
// Fused prep: blocks [0,2048) cvt_hs; [2048,3072) transpose_w; [3072,3074)
// mask_scan.
// ---------------------------------------------------------------------------
__global__ __launch_bounds__(256) void prep(
    const float* __restrict__ hs,
    const float* __restrict__ mask,
    const float* __restrict__ W0, const float* __restrict__ W1,
    const float* __restrict__ W2, const float* __restrict__ W3,
    unsigned short* __restrict__ Ab,
    unsigned short* __restrict__ Wt,
    int* __restrict__ idx, float* __restrict__ bias, int* __restrict__ cnt)
{
    __shared__ unsigned short T[64][72];
    __shared__ int part[256];
    const int bid = blockIdx.x;
    const int tid = threadIdx.x;

    if (bid < 2048) {
        const size_t i = ((size_t)bid * 256 + tid) * 8;
        float4 v0 = *(const float4*)(hs + i);
        float4 v1 = *(const float4*)(hs + i + 4);
        short8 o;
        o[0] = f2b(v0.x); o[1] = f2b(v0.y); o[2] = f2b(v0.z); o[3] = f2b(v0.w);
        o[4] = f2b(v1.x); o[5] = f2b(v1.y); o[6] = f2b(v1.z); o[7] = f2b(v1.w);
        *(short8*)(Ab + i) = o;
    } else if (bid < 3072) {
        const int t = bid - 2048;
        const int z = t >> 8;
        const int n0 = (t & 15) * 64, k0 = ((t >> 4) & 15) * 64;
        const float* W = z == 0 ? W0 : z == 1 ? W1 : z == 2 ? W2 : W3;
        unsigned short* dst = Wt + (size_t)z * HH * HH;
        {
            const int r = tid >> 2, c4 = (tid & 3) * 16;
            const float* src = W + (size_t)(k0 + r) * HH + n0 + c4;
#pragma unroll
            for (int j = 0; j < 16; j += 4) {
                float4 v = *(const float4*)(src + j);
                T[c4 + j + 0][r] = f2b(v.x); T[c4 + j + 1][r] = f2b(v.y);
                T[c4 + j + 2][r] = f2b(v.z); T[c4 + j + 3][r] = f2b(v.w);
            }
        }
        __syncthreads();
        {
            const int n = tid >> 2, sc = (tid & 3) * 2;
#pragma unroll
            for (int u = 0; u < 2; ++u) {
                short8 v = *(const short8*)&T[n][(sc + u) * 8];
                *(short8*)(dst + (size_t)(n0 + n) * HH + k0 + (sc + u) * 8) = v;
            }
        }
    } else {
        const int b = bid - 3072;
        int loc[8]; int m = 0;
        const float* mp = mask + (size_t)b * SS + tid * 8;
#pragma unroll
        for (int j = 0; j < 8; ++j) { loc[j] = (mp[j] == 0.0f) ? 1 : 0; m += loc[j]; }
        part[tid] = m;
        __syncthreads();
        for (int d = 1; d < 256; d <<= 1) {
            int v = (tid >= d) ? part[tid - d] : 0;
            __syncthreads();
            part[tid] += v;
            __syncthreads();
        }
        int base = part[tid] - m;
        const int total = part[255];
#pragma unroll
        for (int j = 0; j < 8; ++j)
            if (loc[j]) idx[(size_t)b * SS + (base++)] = tid * 8 + j;
        if (tid == 0) cnt[b] = total;
        __syncthreads();
        for (int j = tid; j < SS; j += 256) {
            if (j >= total) idx[(size_t)b * SS + j] = 0;
            bias[(size_t)b * SS + j] = (j < total) ? 0.0f : -1e30f;
        }
    }
}

// ---------------------------------------------------------------------------
// QKV GEMM: BK=32 double-buffered, counted vmcnt(4), raw s_barrier.
// Flat grid 768 with XCD-chunked swizzle (T1).
// ---------------------------------------------------------------------------
__global__ __launch_bounds__(256) void gemm_qkv(
    const unsigned short* __restrict__ A, const unsigned short* __restrict__ Bt,
    const float* __restrict__ b0, const float* __restrict__ b1,
    const float* __restrict__ b2, unsigned short* __restrict__ Cout)
{
    __shared__ __align__(16) unsigned short As[2][128 * 32];
    __shared__ __align__(16) unsigned short Bs[2][128 * 32];

    const int f    = blockIdx.x;
    const int wgid = (f & 7) * 96 + (f >> 3);
    const int bx   = wgid % 24;
    const int by   = wgid / 24;

    const int tid = threadIdx.x;
    const int w  = tid >> 6;
    const int l  = tid & 63;
    const int g  = l >> 4, c = l & 15;
    const int wr = w >> 1, wc = w & 1;
    const int m0 = by * 128, n0 = bx * 128;

    const int srow = l >> 2;
    const int gch  = (l & 3) ^ (srow & 3);

    f32x4 acc[4][4];
#pragma unroll
    for (int mi = 0; mi < 4; ++mi)
#pragma unroll
        for (int ni = 0; ni < 4; ++ni)
            acc[mi][ni] = (f32x4){0.f, 0.f, 0.f, 0.f};

#define STAGE(kt_, bb) {                                                      \
    _Pragma("unroll")                                                         \
    for (int u_ = 0; u_ < 2; ++u_) {                                          \
        const int rb_ = (w * 2 + u_) * 16;                                    \
        gl16(A  + (size_t)(m0 + rb_ + srow) * HH + (kt_) * 32 + gch * 8,      \
             (void*)&As[bb][rb_ * 32]);                                       \
        gl16(Bt + (size_t)(n0 + rb_ + srow) * HH + (kt_) * 32 + gch * 8,      \
             (void*)&Bs[bb][rb_ * 32]);                                       \
    } }

    STAGE(0, 0);
    STAGE(1, 1);

    for (int kt = 0; kt < 32; ++kt) {
        const int cb = kt & 1;
        if (kt < 31) asm volatile("s_waitcnt vmcnt(4)" ::: "memory");
        else         asm volatile("s_waitcnt vmcnt(0)" ::: "memory");
        __builtin_amdgcn_s_barrier();
        __builtin_amdgcn_sched_barrier(0);

        short8 af[4], bf[4];
#pragma unroll
        for (int mi = 0; mi < 4; ++mi) {
            const int row = wr * 64 + mi * 16 + c;
            af[mi] = *(const short8*)&As[cb][row * 32 + ((g * 8) ^ ((c & 3) * 8))];
        }
#pragma unroll
        for (int ni = 0; ni < 4; ++ni) {
            const int row = wc * 64 + ni * 16 + c;
            bf[ni] = *(const short8*)&Bs[cb][row * 32 + ((g * 8) ^ ((c & 3) * 8))];
        }
        __builtin_amdgcn_s_setprio(1);
#pragma unroll
        for (int mi = 0; mi < 4; ++mi)
#pragma unroll
            for (int ni = 0; ni < 4; ++ni)
                acc[mi][ni] = __builtin_amdgcn_mfma_f32_16x16x32_bf16(
                    af[mi], bf[ni], acc[mi][ni], 0, 0, 0);
        __builtin_amdgcn_s_setprio(0);

        __builtin_amdgcn_sched_barrier(0);
        __builtin_amdgcn_s_barrier();
        __builtin_amdgcn_sched_barrier(0);
        if (kt + 2 < 32) STAGE(kt + 2, cb);
    }
#undef STAGE

    const int which = n0 >> 10;
    const float* bp = which == 0 ? b0 : which == 1 ? b1 : b2;
    const float scl = which == 0 ? QSCALE : 1.0f;
    unsigned short* dst = Cout + (size_t)which * NTOK * HH;
#pragma unroll
    for (int ni = 0; ni < 4; ++ni) {
        const int nl = (n0 + wc * 64 + ni * 16 + c) & 1023;
        const int h = nl >> 6, d = nl & 63;
        const float bv = bp[nl];
#pragma unroll
        for (int mi = 0; mi < 4; ++mi) {
            const int mBase = m0 + wr * 64 + mi * 16 + g * 4;
#pragma unroll
            for (int j = 0; j < 4; ++j) {
                const int m = mBase + j;
                const int b = m >> 11, si = m & 2047;
                dst[(((size_t)(b * 16 + h)) * SS + si) * 64 + d] =
                    f2b((acc[mi][ni][j] + bv) * scl);
            }
        }
    }
}

// ---------------------------------------------------------------------------
// Out-proj GEMM: 128(M)x64(N) tiles, BK=64 dbuf, counted vmcnt(6).
// Flat grid 512 with XCD-chunked swizzle (T1).
// ---------------------------------------------------------------------------
__global__ __launch_bounds__(256) void gemm_out(
    const unsigned short* __restrict__ A, const unsigned short* __restrict__ Bt,
    const float* __restrict__ b0, float* __restrict__ Cout)
{
    __shared__ __align__(16) unsigned short As[2][128 * 64];
    __shared__ __align__(16) unsigned short Bs[2][64 * 64];

    const int f    = blockIdx.x;
    const int wgid = (f & 7) * 64 + (f >> 3);
    const int bx   = wgid & 15;
    const int by   = wgid >> 4;

    const int tid = threadIdx.x;
    const int w  = tid >> 6;
    const int l  = tid & 63;
    const int g  = l >> 4, c = l & 15;
    const int wr = w >> 1, wc = w & 1;
    const int m0 = by * 128, n0 = bx * 64;

    const int dr = l >> 3;
    const int gc = (l & 7) ^ dr;

    const unsigned short* aBase = A  + (size_t)(m0 + w * 32 + dr) * HH + gc * 8;

    f32x4 acc[4][2];
#pragma unroll
    for (int mi = 0; mi < 4; ++mi)
#pragma unroll
        for (int ni = 0; ni < 2; ++ni)
            acc[mi][ni] = (f32x4){0.f, 0.f, 0.f, 0.f};

    const int swz = (c & 7) * 8;

#define STAGE(kt_, bb) {                                                      \
    const int koff = (kt_) * 64;                                              \
    _Pragma("unroll")                                                         \
    for (int i_ = 0; i_ < 4; ++i_)                                            \
        gl16(aBase + koff + (size_t)i_ * 8 * HH, (void*)&As[bb][(w*4+i_)*512]); \
    _Pragma("unroll")                                                         \
    for (int u_ = 0; u_ < 2; ++u_) {                                          \
        const int rb_ = (w * 2 + u_) * 8;                                     \
        gl16(Bt + (size_t)(n0 + rb_ + dr) * HH + koff + gc * 8,               \
             (void*)&Bs[bb][rb_ * 64]);                                       \
    } }

    STAGE(0, 0);
    STAGE(1, 1);

    for (int kt = 0; kt < 16; ++kt) {
        const int cb = kt & 1;
        if (kt < 15) asm volatile("s_waitcnt vmcnt(6)" ::: "memory");
        else         asm volatile("s_waitcnt vmcnt(0)" ::: "memory");
        __builtin_amdgcn_s_barrier();
        __builtin_amdgcn_sched_barrier(0);

        short8 af[2][4], bf[2][2];
#pragma unroll
        for (int ks = 0; ks < 2; ++ks) {
            const int kb = ks * 32;
#pragma unroll
            for (int mi = 0; mi < 4; ++mi) {
                const int row = wr * 64 + mi * 16 + c;
                af[ks][mi] = *(const short8*)&As[cb][row * 64 + ((kb + g * 8) ^ swz)];
            }
#pragma unroll
            for (int ni = 0; ni < 2; ++ni) {
                const int row = wc * 32 + ni * 16 + c;
                bf[ks][ni] = *(const short8*)&Bs[cb][row * 64 + ((kb + g * 8) ^ swz)];
            }
        }
        __builtin_amdgcn_s_setprio(1);
#pragma unroll
        for (int ks = 0; ks < 2; ++ks)
#pragma unroll
            for (int mi = 0; mi < 4; ++mi)
#pragma unroll
                for (int ni = 0; ni < 2; ++ni)
                    acc[mi][ni] = __builtin_amdgcn_mfma_f32_16x16x32_bf16(
                        af[ks][mi], bf[ks][ni], acc[mi][ni], 0, 0, 0);
        __builtin_amdgcn_s_setprio(0);

        __builtin_amdgcn_sched_barrier(0);
        __builtin_amdgcn_s_barrier();
        __builtin_amdgcn_sched_barrier(0);
        if (kt + 2 < 16) STAGE(kt + 2, cb);
    }
#undef STAGE

#pragma unroll
    for (int ni = 0; ni < 2; ++ni) {
        const int n = n0 + wc * 32 + ni * 16 + c;
        const float bv = b0[n];
#pragma unroll
        for (int mi = 0; mi < 4; ++mi) {
            const int mBase = m0 + wr * 64 + mi * 16 + g * 4;
#pragma unroll
            for (int j = 0; j < 4; ++j)
                Cout[(size_t)(mBase + j) * HH + n] = acc[mi][ni][j] + bv;
        }
    }
}

// ---------------------------------------------------------------------------
// V head-major [bh][s][64] -> Vt [bh][64][j] GATHERED along unmasked idx.
// Early-exit past padded compacted count.
// ---------------------------------------------------------------------------
__global__ __launch_bounds__(256) void vtrans(
    const unsigned short* __restrict__ Vh, const int* __restrict__ idx,
    const int* __restrict__ cntg, unsigned short* __restrict__ Vt)
{
    __shared__ unsigned short T[64][72];
    const int tid = threadIdx.x;
    const int bh = blockIdx.y;
    const int b  = bh >> 4;
    const int s0 = blockIdx.x * 64;

    const int lim = ((cntg[b] + 127) >> 7) << 7;
    if (s0 >= lim) return;

    {
        const int r = tid >> 2, dc = (tid & 3) * 16;
        const int sidx = idx[(size_t)b * SS + s0 + r];
        const unsigned short* src = Vh + ((size_t)bh * SS + sidx) * 64 + dc;
        short8 v0 = *(const short8*)src;
        short8 v1 = *(const short8*)(src + 8);
#pragma unroll
        for (int j = 0; j < 8; ++j) {
            T[dc + j][r]     = (unsigned short)v0[j];
            T[dc + 8 + j][r] = (unsigned short)v1[j];
        }
    }
    __syncthreads();
    {
        const int d = tid >> 2, sc = (tid & 3) * 2;
#pragma unroll
        for (int u = 0; u < 2; ++u) {
            short8 v = *(const short8*)&T[d][(sc + u) * 8];
            *(short8*)(Vt + ((size_t)bh * 64 + d) * SS + s0 + (sc + u) * 8) = v;
        }
    }
}

// ---------------------------------------------------------------------------
// Flash attention over COMPACTED keys (exact). Swapped-QK^T 32x32x16,
// no-max log2 softmax. Block = 8 waves x 32q = 256 q (512 thr): halves
// per-(b,h) K/V staging vs 128q blocks while keeping 2 waves/SIMD.
// 128-key double-buffered tiles, reg-staged prefetch (T14), K gathered via
// idx at stage time. Bias only on boundary tile. Grid 256 (1/CU), XCD T1.
// ---------------------------------------------------------------------------
__global__ __launch_bounds__(512) void attn_mfma(
    const unsigned short* __restrict__ Qb, const unsigned short* __restrict__ Kb,
    const unsigned short* __restrict__ Vtb, const float* __restrict__ biasg,
    const int* __restrict__ idxg, const int* __restrict__ cntg,
    unsigned short* __restrict__ ctx)
{
    __shared__ __align__(16) unsigned short Ks[2][128 * 64];   // [key][d] 128B rows
    __shared__ __align__(16) unsigned short Vts[2][64 * 128];  // [d][key] 256B rows
    __shared__ float Sc[8][32];

    // XCD swizzle: 256 blocks, 8 XCDs -> 32-block contiguous chunks
    const int wg  = blockIdx.x;
    const int swg = (wg & 7) * 32 + (wg >> 3);
    const int qx  = swg & 7;        // 8 q-blocks of 256
    const int bh  = swg >> 3;       // 32

    const int tid = threadIdx.x;
    const int l   = tid & 63;
    const int wq  = tid >> 6;       // wave 0..7
    const int hi  = l >> 5;
    const int c   = l & 31;
    const int b   = bh >> 4, h = bh & 15;
    const int q0  = qx * 256 + wq * 32;

    const unsigned short* Qp = Qb  + (size_t)bh * SS * 64;
    const unsigned short* Kp = Kb  + (size_t)bh * SS * 64;
    const unsigned short* Vp = Vtb + (size_t)bh * 64 * SS;
    const float* biasp = biasg + (size_t)b * SS;
    const int* idxb = idxg + (size_t)b * SS;

    const int cnt    = cntg[b];
    const int nt     = (cnt + 127) >> 7;   // 128-key tiles (<= 16)
    const int ntFull = cnt >> 7;           // fully-real tiles

    // staging maps (512 threads)
    const int sr  = tid >> 3;        // K rows: sr, sr+64  (0..63)
    const int sc8 = tid & 7;         // K 16B chunk (of 8)
    const int vd  = tid >> 3;        // V^T row (d) 0..63
    const int vc0 = (tid & 7) * 2;   // V 16B chunks vc0, vc0+1 (of 16)

    short8 qf[4];
    {
        const unsigned short* qrow = Qp + (size_t)(q0 + c) * 64 + hi * 8;
#pragma unroll
        for (int s = 0; s < 4; ++s) qf[s] = *(const short8*)(qrow + s * 16);
    }

    f32x16 oacc[2];
#pragma unroll
    for (int dt = 0; dt < 2; ++dt)
#pragma unroll
        for (int r = 0; r < 16; ++r) oacc[dt][r] = 0.f;

    float ls[4] = {0.f, 0.f, 0.f, 0.f};

    short8 kr0, kr1, vr0, vr1;

#define LOADREG(t_) {                                                         \
    const int* ip_ = idxb + (t_) * 128;                                       \
    kr0 = *(const short8*)(Kp + (size_t)ip_[sr      ] * 64 + sc8 * 8);        \
    kr1 = *(const short8*)(Kp + (size_t)ip_[sr + 64 ] * 64 + sc8 * 8);        \
    const unsigned short* vp_ = Vp + (size_t)vd * SS + (t_) * 128;            \
    vr0 = *(const short8*)(vp_ + (vc0 + 0) * 8);                              \
    vr1 = *(const short8*)(vp_ + (vc0 + 1) * 8); }

#define DSWRITE(bb) {                                                         \
    *(short8*)((char*)Ks[bb] + (sr      ) * 128 + SWZ16(sr,      sc8 * 16)) = kr0; \
    *(short8*)((char*)Ks[bb] + (sr + 64 ) * 128 + SWZ16(sr + 64, sc8 * 16)) = kr1; \
    *(short8*)((char*)Vts[bb] + vd * 256 + VSWZ(vd, (vc0 + 0) * 16)) = vr0;   \
    *(short8*)((char*)Vts[bb] + vd * 256 + VSWZ(vd, (vc0 + 1) * 16)) = vr1; }

    LOADREG(0);
    DSWRITE(0);
    __syncthreads();

    for (int t = 0; t < nt; ++t) {
        const int cb = t & 1;
        if (t + 1 < nt) LOADREG(t + 1);   // in flight during compute
        const bool needBias = (t >= ntFull);

#pragma unroll
        for (int hh = 0; hh < 4; ++hh) {   // four 32-key halves
            f32x16 s4h;
#pragma unroll
            for (int r = 0; r < 16; ++r) s4h[r] = 0.f;
            const int krow = hh * 32 + c;
            __builtin_amdgcn_s_setprio(1);
#pragma unroll
            for (int ss = 0; ss < 4; ++ss) {
                short8 kf = *(const short8*)((char*)Ks[cb] + krow * 128 +
                                             SWZ16(krow, (ss * 2 + hi) * 16));
                s4h = __builtin_amdgcn_mfma_f32_32x32x16_bf16(kf, qf[ss], s4h, 0, 0, 0);
            }
            __builtin_amdgcn_s_setprio(0);

            float pvv[16];
            if (needBias) {
                f32x4 mqh[4];
#pragma unroll
                for (int tt = 0; tt < 4; ++tt)
                    mqh[tt] = *(const f32x4*)(biasp + t * 128 + hh * 32 + tt * 8 + hi * 4);
#pragma unroll
                for (int r = 0; r < 16; ++r)
                    pvv[r] = exp2fast(s4h[r] + mqh[r >> 2][r & 3]);
            } else {
#pragma unroll
                for (int r = 0; r < 16; ++r)
                    pvv[r] = exp2fast(s4h[r]);
            }
#pragma unroll
            for (int r = 0; r < 16; ++r) ls[r & 3] += pvv[r];

            unsigned wdh[8];
#pragma unroll
            for (int j = 0; j < 8; ++j) wdh[j] = pk2a(pvv[2 * j], pvv[2 * j + 1]);
#pragma unroll
            for (int g4 = 0; g4 < 2; ++g4) {
                asm volatile("v_permlane32_swap_b32 %0, %1"
                             : "+v"(wdh[4 * g4 + 0]), "+v"(wdh[4 * g4 + 2]));
                asm volatile("v_permlane32_swap_b32 %0, %1"
                             : "+v"(wdh[4 * g4 + 1]), "+v"(wdh[4 * g4 + 3]));
            }

            __builtin_amdgcn_s_setprio(1);
#pragma unroll
            for (int s2 = 0; s2 < 2; ++s2) {
                const int vchunk = hh * 4 + s2 * 2 + hi;   // 16-key slice (of 16)
                union { unsigned u[4]; short8 s8; } pa;
#pragma unroll
                for (int u_ = 0; u_ < 4; ++u_) pa.u[u_] = wdh[4 * s2 + u_];
#pragma unroll
                for (int dt = 0; dt < 2; ++dt) {
                    const int vrow = dt * 32 + c;
                    short8 vf = *(const short8*)((char*)Vts[cb] + vrow * 256 +
                                                 VSWZ(vrow, vchunk * 16));
                    oacc[dt] = __builtin_amdgcn_mfma_f32_32x32x16_bf16(pa.s8, vf, oacc[dt], 0, 0, 0);
                }
            }
            __builtin_amdgcn_s_setprio(0);
        }

        if (t + 1 < nt) DSWRITE(cb ^ 1);   // buffer not being read this iter
        __syncthreads();                   // writes visible; all reads of cb done
    }
#undef LOADREG
#undef DSWRITE

    // ---- epilogue: per-wave l reduce + broadcast to D-row layout ----
    float lsum = (ls[0] + ls[1]) + (ls[2] + ls[3]);
    lsum += __shfl_xor(lsum, 32, 64);

    Sc[wq][c] = lsum;
    asm volatile("s_waitcnt lgkmcnt(0)" ::: "memory");
    f32x4 lq[4];
#pragma unroll
    for (int tt = 0; tt < 4; ++tt)
        lq[tt] = *(const f32x4*)&Sc[wq][tt * 8 + hi * 4];

#pragma unroll
    for (int dt = 0; dt < 2; ++dt)
#pragma unroll
        for (int r = 0; r < 16; ++r) {
            const int row = (r & 3) + 8 * (r >> 2) + 4 * hi;
            const float val = oacc[dt][r] / lq[r >> 2][r & 3];
            ctx[((size_t)(b * SS + q0 + row)) * HH + h * 64 + dt * 32 + c] = f2b(val);
        }
}

// ---------------------------------------------------------------------------
extern "C" void kernel_launch(void* const* d_in, const int* in_sizes, int n_in,
                              void* d_out, int out_size, void* d_ws, size_t ws_size,
                              hipStream_t stream)
{
    const float* hs   = (const float*)d_in[0];
    const float* mask = (const float*)d_in[1];
    const float* Wq   = (const float*)d_in[2];
    const float* bq   = (const float*)d_in[3];
    const float* Wk   = (const float*)d_in[4];
    const float* bk   = (const float*)d_in[5];
    const float* Wv   = (const float*)d_in[6];
    const float* bv   = (const float*)d_in[7];
    const float* Wo   = (const float*)d_in[8];
    const float* bo   = (const float*)d_in[9];
    float* out = (float*)d_out;

    unsigned short* Ab   = (unsigned short*)d_ws;
    unsigned short* Wt   = Ab + (size_t)NTOK * HH;
    unsigned short* Qh   = Wt + (size_t)4 * HH * HH;   // Qh|Kh|Vh contiguous
    unsigned short* Kh   = Qh + (size_t)NTOK * HH;
    unsigned short* Vh   = Kh + (size_t)NTOK * HH;
    unsigned short* Vt   = Vh + (size_t)NTOK * HH;
    unsigned short* ctxb = Vt + (size_t)NTOK * HH;
    float* biasb = (float*)(ctxb + (size_t)NTOK * HH);
    int*   idxb  = (int*)(biasb + (size_t)NB * SS);
    int*   cntb  = idxb + (size_t)NB * SS;

    dim3 blk(256);

    prep<<<dim3(3074), blk, 0, stream>>>(hs, mask, Wq, Wk, Wv, Wo,
                                         Ab, Wt, idxb, biasb, cntb);

    gemm_qkv<<<dim3(768), blk, 0, stream>>>(Ab, Wt, bq, bk, bv, Qh);

    vtrans<<<dim3(SS / 64, NB * NHEAD), blk, 0, stream>>>(Vh, idxb, cntb, Vt);

    attn_mfma<<<dim3(256), dim3(512), 0, stream>>>(Qh, Kh, Vt, biasb, idxb, cntb, ctxb);

    gemm_out<<<dim3(512), blk, 0, stream>>>(ctxb, Wt + 3 * (size_t)HH * HH,
                                            bo, out);
}